// Round 3
// baseline (554.543 us; speedup 1.0000x reference)
//
#include <hip/hip_runtime.h>

// GCN 2-layer via on-device CSR + gather-aggregation.
// out = A_norm * relu(A_norm * (X W1) + b1) * W2 + b2
// CSR build = two-level counting sort with locality-preserving writes:
//   bucket = dst>>8 (256 nodes/bucket). Pass A: per-chunk bucket histograms.
//   Scan: one linear exclusive scan over bucket-major (b, chunk) counts.
//   Pass B: partition edges (packed src|dstl<<24) into WG-private runs.
//   Pass C: per-bucket local counting sort in LDS -> rowptr/dinv/csr.

#define NPB 256              // nodes per bucket (pow2, dst>>8)
#define NB_MAX 512           // max buckets supported (N <= 131072)
#define NCH 256              // partition chunks (= WGs)

// ---- Pass A: per-chunk bucket histogram -> ghist[b*NCH + w] ----
__global__ __launch_bounds__(256) void k_hist(const int* __restrict__ dst, int* __restrict__ ghist,
                                              int E, int NB, int chunk) {
    __shared__ int h[NB_MAX];
    int tid = threadIdx.x, w = blockIdx.x;
    for (int b = tid; b < NB; b += 256) h[b] = 0;
    __syncthreads();
    int beg = w * chunk, end = min(E, beg + chunk);
    for (int e = beg + tid; e < end; e += 256) atomicAdd(&h[dst[e] >> 8], 1);
    __syncthreads();
    for (int b = tid; b < NB; b += 256) ghist[b * NCH + w] = h[b];
}

// ---- linear exclusive scan of ghist[M] -> gbase[M]; bucketBase[b] = gbase[b*NCH] ----
__global__ __launch_bounds__(1024) void k_scan(const int* __restrict__ ghist, int* __restrict__ gbase,
                                               int* __restrict__ bucketBase, int NB, int E) {
    __shared__ int part[1024];
    int tid = threadIdx.x;
    int M = NB * NCH;
    int L = (M + 1023) / 1024;
    int beg = tid * L, end = min(M, beg + L);
    int s = 0;
    for (int i = beg; i < end; ++i) s += ghist[i];
    part[tid] = s;
    __syncthreads();
    // Hillis-Steele inclusive scan over 1024 partials
    for (int off = 1; off < 1024; off <<= 1) {
        int add = (tid >= off) ? part[tid - off] : 0;
        __syncthreads();
        part[tid] += add;
        __syncthreads();
    }
    int run = part[tid] - s;  // exclusive base for this thread's segment
    for (int i = beg; i < end; ++i) {
        int v = ghist[i];
        gbase[i] = run;
        run += v;
    }
    __syncthreads();
    for (int b = tid; b < NB; b += 1024) bucketBase[b] = gbase[b * NCH];
    if (tid == 0) bucketBase[NB] = E;
}

// ---- Pass B: partition edges into WG-private contiguous runs ----
__global__ __launch_bounds__(256) void k_partition(const int* __restrict__ src, const int* __restrict__ dst,
                                                   const int* __restrict__ gbase, unsigned int* __restrict__ ebuf,
                                                   int E, int NB, int chunk) {
    __shared__ int cur[NB_MAX];
    int tid = threadIdx.x, w = blockIdx.x;
    for (int b = tid; b < NB; b += 256) cur[b] = gbase[b * NCH + w];
    __syncthreads();
    int beg = w * chunk, end = min(E, beg + chunk);
    for (int e = beg + tid; e < end; e += 256) {
        int d = dst[e];
        int b = d >> 8;
        int pos = atomicAdd(&cur[b], 1);
        ebuf[pos] = (unsigned int)src[e] | ((unsigned int)(d & 255) << 24);  // src < 2^24
    }
}

// ---- Pass C: per-bucket counting sort -> rowptr, dinv, csr ----
__global__ __launch_bounds__(256) void k_csr(const unsigned int* __restrict__ ebuf,
                                             const int* __restrict__ bucketBase,
                                             int* __restrict__ rowptr, float* __restrict__ dinv,
                                             int* __restrict__ csr, int n, int E) {
    __shared__ int cnt[NPB];
    __shared__ int sc[NPB];
    __shared__ int cur[NPB];
    int tid = threadIdx.x, b = blockIdx.x;
    int ebeg = bucketBase[b], eend = bucketBase[b + 1];
    cnt[tid] = 0;
    __syncthreads();
    for (int i = ebeg + tid; i < eend; i += 256) atomicAdd(&cnt[ebuf[i] >> 24], 1);
    __syncthreads();
    int v = cnt[tid];
    sc[tid] = v;
    __syncthreads();
    for (int off = 1; off < 256; off <<= 1) {
        int add = (tid >= off) ? sc[tid - off] : 0;
        __syncthreads();
        sc[tid] += add;
        __syncthreads();
    }
    int ex = sc[tid] - v;  // exclusive
    cur[tid] = ex;
    int node = b * NPB + tid;
    if (node < n) {
        rowptr[node] = ebeg + ex;
        dinv[node] = rsqrtf((float)(v + 1));  // +1 self-loop
    }
    if (b == 0 && tid == 0) rowptr[n] = E;
    __syncthreads();
    for (int i = ebeg + tid; i < eend; i += 256) {
        unsigned int word = ebuf[i];
        int pos = atomicAdd(&cur[word >> 24], 1);
        csr[ebeg + pos] = (int)(word & 0xFFFFFFu);
    }
}

// ---- g1[row] = (x[row] @ W1) * dinv[row];  [N,128]@[128,64] ----
__global__ __launch_bounds__(256) void k_gemm1(const float* __restrict__ x, const float* __restrict__ W1,
                                               const float* __restrict__ dinv, float* __restrict__ g1,
                                               int n) {
    __shared__ float Ws[128 * 64];   // 32 KB
    __shared__ float xs[4][128];
    int tid = threadIdx.x;
    for (int i = tid; i < 128 * 64; i += 256) Ws[i] = W1[i];
    int nrg = n >> 2;
    int r = tid >> 6, col = tid & 63;
    for (int rg = blockIdx.x; rg < nrg; rg += gridDim.x) {
        __syncthreads();
        int row0 = rg << 2;
        for (int i = tid; i < 512; i += 256) xs[i >> 7][i & 127] = x[row0 * 128 + i];
        __syncthreads();
        float acc = 0.f;
#pragma unroll
        for (int k = 0; k < 128; ++k) acc += xs[r][k] * Ws[k * 64 + col];
        int row = row0 + r;
        g1[row * 64 + col] = acc * dinv[row];
    }
}

// ---- layer-1 aggregation: agg1[v] = dinv[v]*(g1[v] + sum_{s in N(v)} g1[s]) ----
__global__ __launch_bounds__(256) void k_agg1(const float* __restrict__ g1, const int* __restrict__ rowptr,
                                              const int* __restrict__ csr, const float* __restrict__ dinv,
                                              float* __restrict__ agg1, int n) {
    int lane = threadIdx.x & 63;
    int v = blockIdx.x * 4 + (threadIdx.x >> 6);
    if (v >= n) return;
    int beg = rowptr[v], end = rowptr[v + 1];
    int sub = lane >> 4, fl = lane & 15;
    float4 acc = {0.f, 0.f, 0.f, 0.f};
    for (int i = beg + sub; i < end; i += 4) {
        int s = csr[i];
        float4 r = *reinterpret_cast<const float4*>(&g1[(size_t)s * 64 + fl * 4]);
        acc.x += r.x; acc.y += r.y; acc.z += r.z; acc.w += r.w;
    }
#pragma unroll
    for (int off = 16; off < 64; off <<= 1) {
        acc.x += __shfl_xor(acc.x, off);
        acc.y += __shfl_xor(acc.y, off);
        acc.z += __shfl_xor(acc.z, off);
        acc.w += __shfl_xor(acc.w, off);
    }
    if (sub == 0) {
        float4 self = *reinterpret_cast<const float4*>(&g1[(size_t)v * 64 + fl * 4]);
        float d = dinv[v];
        float4 o;
        o.x = (acc.x + self.x) * d;
        o.y = (acc.y + self.y) * d;
        o.z = (acc.z + self.z) * d;
        o.w = (acc.w + self.w) * d;
        *reinterpret_cast<float4*>(&agg1[(size_t)v * 64 + fl * 4]) = o;
    }
}

// ---- g2[row] = (relu(agg1[row] + b1) @ W2) * dinv[row];  [N,64]@[64,40] ----
__global__ __launch_bounds__(256) void k_gemm2(const float* __restrict__ agg1, const float* __restrict__ W2,
                                               const float* __restrict__ b1, const float* __restrict__ dinv,
                                               float* __restrict__ g2, int n) {
    __shared__ float Ws[64 * 40];
    __shared__ float xs[32][65];
    int tid = threadIdx.x;
    for (int i = tid; i < 64 * 40; i += 256) Ws[i] = W2[i];
    int nrg = n >> 5;
    int r = tid >> 3, cb = (tid & 7) * 5;
    for (int rg = blockIdx.x; rg < nrg; rg += gridDim.x) {
        __syncthreads();
        int row0 = rg << 5;
        for (int i = tid; i < 32 * 64; i += 256) {
            int rr = i >> 6, k = i & 63;
            float vv = agg1[(row0 + rr) * 64 + k] + b1[k];
            xs[rr][k] = vv > 0.f ? vv : 0.f;
        }
        __syncthreads();
        float acc[5] = {0.f, 0.f, 0.f, 0.f, 0.f};
#pragma unroll
        for (int k = 0; k < 64; ++k) {
            float xv = xs[r][k];
#pragma unroll
            for (int j = 0; j < 5; ++j) acc[j] += xv * Ws[k * 40 + cb + j];
        }
        int row = row0 + r;
        float di = dinv[row];
#pragma unroll
        for (int j = 0; j < 5; ++j) g2[row * 40 + cb + j] = acc[j] * di;
    }
}

// ---- layer-2 aggregation + bias: out[v] = dinv[v]*(g2[v] + sum g2[s]) + b2 ----
__global__ __launch_bounds__(256) void k_agg2(const float* __restrict__ g2, const int* __restrict__ rowptr,
                                              const int* __restrict__ csr, const float* __restrict__ dinv,
                                              const float* __restrict__ b2, float* __restrict__ out, int n) {
    int lane = threadIdx.x & 63;
    int v = blockIdx.x * 4 + (threadIdx.x >> 6);
    if (v >= n) return;
    int beg = rowptr[v], end = rowptr[v + 1];
    int sub = lane >> 4, fl = lane & 15;
    float4 acc = {0.f, 0.f, 0.f, 0.f};
    if (fl < 10) {
        for (int i = beg + sub; i < end; i += 4) {
            int s = csr[i];
            float4 r = *reinterpret_cast<const float4*>(&g2[(size_t)s * 40 + fl * 4]);
            acc.x += r.x; acc.y += r.y; acc.z += r.z; acc.w += r.w;
        }
    }
#pragma unroll
    for (int off = 16; off < 64; off <<= 1) {
        acc.x += __shfl_xor(acc.x, off);
        acc.y += __shfl_xor(acc.y, off);
        acc.z += __shfl_xor(acc.z, off);
        acc.w += __shfl_xor(acc.w, off);
    }
    if (sub == 0 && fl < 10) {
        float4 self = *reinterpret_cast<const float4*>(&g2[(size_t)v * 40 + fl * 4]);
        float4 bb = *reinterpret_cast<const float4*>(&b2[fl * 4]);
        float d = dinv[v];
        float4 o;
        o.x = (acc.x + self.x) * d + bb.x;
        o.y = (acc.y + self.y) * d + bb.y;
        o.z = (acc.z + self.z) * d + bb.z;
        o.w = (acc.w + self.w) * d + bb.w;
        *reinterpret_cast<float4*>(&out[(size_t)v * 40 + fl * 4]) = o;
    }
}

extern "C" void kernel_launch(void* const* d_in, const int* in_sizes, int n_in,
                              void* d_out, int out_size, void* d_ws, size_t ws_size,
                              hipStream_t stream) {
    const float* x  = (const float*)d_in[0];
    const int*   ei = (const int*)d_in[1];
    const float* W1 = (const float*)d_in[2];
    const float* b1 = (const float*)d_in[3];
    const float* W2 = (const float*)d_in[4];
    const float* b2 = (const float*)d_in[5];
    float* out = (float*)d_out;

    int N = in_sizes[0] / 128;   // 100000
    int E = in_sizes[1] / 2;     // 1600000
    const int* src = ei;
    const int* dst = ei + E;

    int NB = (N + NPB - 1) / NPB;      // 391 buckets
    int chunk = (E + NCH - 1) / NCH;   // 6250

    char* w = (char*)d_ws;
    int*   ghist      = (int*)w;           w += (size_t)NB * NCH * 4;
    int*   gbase      = (int*)w;           w += (size_t)NB * NCH * 4;
    int*   bucketBase = (int*)w;           w += (size_t)(NB + 1) * 4 + 252;
    unsigned int* ebuf = (unsigned int*)w; w += (size_t)E * 4;
    int*   rowptr     = (int*)w;           w += (size_t)(N + 1) * 4 + 252;
    float* dinv       = (float*)w;         w += (size_t)N * 4 + 256;
    int*   csr        = (int*)w;           w += (size_t)E * 4;
    float* g1         = (float*)w;         w += (size_t)N * 64 * 4;
    float* agg1       = (float*)w;         // N*64*4
    float* g2         = g1;                // g1 dead after k_agg1

    k_hist<<<NCH, 256, 0, stream>>>(dst, ghist, E, NB, chunk);
    k_scan<<<1, 1024, 0, stream>>>(ghist, gbase, bucketBase, NB, E);
    k_partition<<<NCH, 256, 0, stream>>>(src, dst, gbase, ebuf, E, NB, chunk);
    k_csr<<<NB, 256, 0, stream>>>(ebuf, bucketBase, rowptr, dinv, csr, N, E);

    k_gemm1<<<1024, 256, 0, stream>>>(x, W1, dinv, g1, N);
    k_agg1<<<(N + 3) / 4, 256, 0, stream>>>(g1, rowptr, csr, dinv, agg1, N);
    k_gemm2<<<1024, 256, 0, stream>>>(agg1, W2, b1, dinv, g2, N);
    k_agg2<<<(N + 3) / 4, 256, 0, stream>>>(g2, rowptr, csr, dinv, b2, out, N);
}

// Round 4
// 402.493 us; speedup vs baseline: 1.3778x; 1.3778x over previous
//
#include <hip/hip_runtime.h>

// GCN 2-layer via on-device CSR + gather-aggregation.
// out = A_norm * relu(A_norm * (X W1) + b1) * W2 + b2
// CSR build = two-level counting sort with locality-preserving writes:
//   bucket = dst>>8 (256 nodes/bucket). Pass A: per-chunk bucket histograms.
//   Scan: 3-phase device-wide exclusive scan of bucket-major (b, chunk) counts.
//   Pass B: partition edges (packed src|dstl<<24) into WG-private runs.
//   Pass C: per-bucket local counting sort in LDS -> rowptr/dinv/csr.

#define NPB 256              // nodes per bucket (pow2, dst>>8)
#define NB_MAX 512           // max buckets supported (N <= 131072)
#define NCH 256              // partition chunks (= WGs)
#define SCAN_BLK 1024        // elements per scan WG

// ---- Pass A: per-chunk bucket histogram -> ghist[b*NCH + w] ----
__global__ __launch_bounds__(256) void k_hist(const int* __restrict__ dst, int* __restrict__ ghist,
                                              int E, int NB, int chunk) {
    __shared__ int h[NB_MAX];
    int tid = threadIdx.x, w = blockIdx.x;
    for (int b = tid; b < NB; b += 256) h[b] = 0;
    __syncthreads();
    int beg = w * chunk, end = min(E, beg + chunk);
    for (int e = beg + tid; e < end; e += 256) atomicAdd(&h[dst[e] >> 8], 1);
    __syncthreads();
    for (int b = tid; b < NB; b += 256) ghist[b * NCH + w] = h[b];
}

// ---- 3-phase exclusive scan of ghist[M] -> gbase[M], bucketBase ----
__global__ __launch_bounds__(256) void k_scan_reduce(const int* __restrict__ ghist, int* __restrict__ wsum, int M) {
    __shared__ int s[256];
    int tid = threadIdx.x;
    int base = blockIdx.x * SCAN_BLK + tid * 4;
    int v = 0;
    if (base + 3 < M) {
        int4 r = *reinterpret_cast<const int4*>(&ghist[base]);
        v = r.x + r.y + r.z + r.w;
    } else {
        for (int j = 0; j < 4; ++j) if (base + j < M) v += ghist[base + j];
    }
    s[tid] = v;
    __syncthreads();
    for (int off = 128; off > 0; off >>= 1) {
        if (tid < off) s[tid] += s[tid + off];
        __syncthreads();
    }
    if (tid == 0) wsum[blockIdx.x] = s[0];
}

// single WG: exclusive-scan nw (<=128) block sums in place; set bucketBase[NB]=E
__global__ __launch_bounds__(128) void k_scan_mid(int* __restrict__ wsum, int* __restrict__ bucketBase,
                                                  int nw, int NB, int E) {
    __shared__ int s[128];
    int tid = threadIdx.x;
    int v = (tid < nw) ? wsum[tid] : 0;
    s[tid] = v;
    __syncthreads();
    for (int off = 1; off < 128; off <<= 1) {
        int add = (tid >= off) ? s[tid - off] : 0;
        __syncthreads();
        s[tid] += add;
        __syncthreads();
    }
    if (tid < nw) wsum[tid] = s[tid] - v;  // exclusive
    if (tid == 0) bucketBase[NB] = E;
}

__global__ __launch_bounds__(256) void k_scan_apply(const int* __restrict__ ghist, const int* __restrict__ wsum,
                                                    int* __restrict__ gbase, int* __restrict__ bucketBase, int M) {
    __shared__ int s[256];
    int tid = threadIdx.x;
    int base = blockIdx.x * SCAN_BLK + tid * 4;
    int e[4];
    int v = 0;
#pragma unroll
    for (int j = 0; j < 4; ++j) {
        int val = (base + j < M) ? ghist[base + j] : 0;
        e[j] = v;  // thread-local exclusive prefix
        v += val;
    }
    s[tid] = v;
    __syncthreads();
    for (int off = 1; off < 256; off <<= 1) {
        int add = (tid >= off) ? s[tid - off] : 0;
        __syncthreads();
        s[tid] += add;
        __syncthreads();
    }
    int tbase = wsum[blockIdx.x] + s[tid] - v;
#pragma unroll
    for (int j = 0; j < 4; ++j) {
        int i = base + j;
        if (i < M) {
            int g = tbase + e[j];
            gbase[i] = g;
            if ((i & (NCH - 1)) == 0) bucketBase[i / NCH] = g;  // first chunk of bucket
        }
    }
}

// ---- Pass B: partition edges into WG-private contiguous runs ----
__global__ __launch_bounds__(256) void k_partition(const int* __restrict__ src, const int* __restrict__ dst,
                                                   const int* __restrict__ gbase, unsigned int* __restrict__ ebuf,
                                                   int E, int NB, int chunk) {
    __shared__ int cur[NB_MAX];
    int tid = threadIdx.x, w = blockIdx.x;
    for (int b = tid; b < NB; b += 256) cur[b] = gbase[b * NCH + w];
    __syncthreads();
    int beg = w * chunk, end = min(E, beg + chunk);
    for (int e = beg + tid; e < end; e += 256) {
        int d = dst[e];
        int b = d >> 8;
        int pos = atomicAdd(&cur[b], 1);
        ebuf[pos] = (unsigned int)src[e] | ((unsigned int)(d & 255) << 24);  // src < 2^24
    }
}

// ---- Pass C: per-bucket counting sort -> rowptr, dinv, csr ----
__global__ __launch_bounds__(256) void k_csr(const unsigned int* __restrict__ ebuf,
                                             const int* __restrict__ bucketBase,
                                             int* __restrict__ rowptr, float* __restrict__ dinv,
                                             int* __restrict__ csr, int n, int E) {
    __shared__ int cnt[NPB];
    __shared__ int sc[NPB];
    __shared__ int cur[NPB];
    int tid = threadIdx.x, b = blockIdx.x;
    int ebeg = bucketBase[b], eend = bucketBase[b + 1];
    cnt[tid] = 0;
    __syncthreads();
    for (int i = ebeg + tid; i < eend; i += 256) atomicAdd(&cnt[ebuf[i] >> 24], 1);
    __syncthreads();
    int v = cnt[tid];
    sc[tid] = v;
    __syncthreads();
    for (int off = 1; off < 256; off <<= 1) {
        int add = (tid >= off) ? sc[tid - off] : 0;
        __syncthreads();
        sc[tid] += add;
        __syncthreads();
    }
    int ex = sc[tid] - v;  // exclusive
    cur[tid] = ex;
    int node = b * NPB + tid;
    if (node < n) {
        rowptr[node] = ebeg + ex;
        dinv[node] = rsqrtf((float)(v + 1));  // +1 self-loop
    }
    if (b == 0 && tid == 0) rowptr[n] = E;
    __syncthreads();
    for (int i = ebeg + tid; i < eend; i += 256) {
        unsigned int word = ebuf[i];
        int pos = atomicAdd(&cur[word >> 24], 1);
        csr[ebeg + pos] = (int)(word & 0xFFFFFFu);
    }
}

// ---- g1[row] = (x[row] @ W1) * dinv[row];  [N,128]@[128,64] ----
__global__ __launch_bounds__(256) void k_gemm1(const float* __restrict__ x, const float* __restrict__ W1,
                                               const float* __restrict__ dinv, float* __restrict__ g1,
                                               int n) {
    __shared__ float Ws[128 * 64];   // 32 KB
    __shared__ float xs[4][128];
    int tid = threadIdx.x;
    for (int i = tid; i < 128 * 64; i += 256) Ws[i] = W1[i];
    int nrg = n >> 2;
    int r = tid >> 6, col = tid & 63;
    for (int rg = blockIdx.x; rg < nrg; rg += gridDim.x) {
        __syncthreads();
        int row0 = rg << 2;
        for (int i = tid; i < 512; i += 256) xs[i >> 7][i & 127] = x[row0 * 128 + i];
        __syncthreads();
        float acc = 0.f;
#pragma unroll
        for (int k = 0; k < 128; ++k) acc += xs[r][k] * Ws[k * 64 + col];
        int row = row0 + r;
        g1[row * 64 + col] = acc * dinv[row];
    }
}

// ---- layer-1 aggregation: agg1[v] = dinv[v]*(g1[v] + sum_{s in N(v)} g1[s]) ----
__global__ __launch_bounds__(256) void k_agg1(const float* __restrict__ g1, const int* __restrict__ rowptr,
                                              const int* __restrict__ csr, const float* __restrict__ dinv,
                                              float* __restrict__ agg1, int n) {
    int lane = threadIdx.x & 63;
    int v = blockIdx.x * 4 + (threadIdx.x >> 6);
    if (v >= n) return;
    int beg = rowptr[v], end = rowptr[v + 1];
    int sub = lane >> 4, fl = lane & 15;
    float4 acc = {0.f, 0.f, 0.f, 0.f};
    for (int i = beg + sub; i < end; i += 4) {
        int s = csr[i];
        float4 r = *reinterpret_cast<const float4*>(&g1[(size_t)s * 64 + fl * 4]);
        acc.x += r.x; acc.y += r.y; acc.z += r.z; acc.w += r.w;
    }
#pragma unroll
    for (int off = 16; off < 64; off <<= 1) {
        acc.x += __shfl_xor(acc.x, off);
        acc.y += __shfl_xor(acc.y, off);
        acc.z += __shfl_xor(acc.z, off);
        acc.w += __shfl_xor(acc.w, off);
    }
    if (sub == 0) {
        float4 self = *reinterpret_cast<const float4*>(&g1[(size_t)v * 64 + fl * 4]);
        float d = dinv[v];
        float4 o;
        o.x = (acc.x + self.x) * d;
        o.y = (acc.y + self.y) * d;
        o.z = (acc.z + self.z) * d;
        o.w = (acc.w + self.w) * d;
        *reinterpret_cast<float4*>(&agg1[(size_t)v * 64 + fl * 4]) = o;
    }
}

// ---- g2[row] = (relu(agg1[row] + b1) @ W2) * dinv[row];  [N,64]@[64,40] ----
__global__ __launch_bounds__(256) void k_gemm2(const float* __restrict__ agg1, const float* __restrict__ W2,
                                               const float* __restrict__ b1, const float* __restrict__ dinv,
                                               float* __restrict__ g2, int n) {
    __shared__ float Ws[64 * 40];
    __shared__ float xs[32][65];
    int tid = threadIdx.x;
    for (int i = tid; i < 64 * 40; i += 256) Ws[i] = W2[i];
    int nrg = n >> 5;
    int r = tid >> 3, cb = (tid & 7) * 5;
    for (int rg = blockIdx.x; rg < nrg; rg += gridDim.x) {
        __syncthreads();
        int row0 = rg << 5;
        for (int i = tid; i < 32 * 64; i += 256) {
            int rr = i >> 6, k = i & 63;
            float vv = agg1[(row0 + rr) * 64 + k] + b1[k];
            xs[rr][k] = vv > 0.f ? vv : 0.f;
        }
        __syncthreads();
        float acc[5] = {0.f, 0.f, 0.f, 0.f, 0.f};
#pragma unroll
        for (int k = 0; k < 64; ++k) {
            float xv = xs[r][k];
#pragma unroll
            for (int j = 0; j < 5; ++j) acc[j] += xv * Ws[k * 40 + cb + j];
        }
        int row = row0 + r;
        float di = dinv[row];
#pragma unroll
        for (int j = 0; j < 5; ++j) g2[row * 40 + cb + j] = acc[j] * di;
    }
}

// ---- layer-2 aggregation + bias: out[v] = dinv[v]*(g2[v] + sum g2[s]) + b2 ----
__global__ __launch_bounds__(256) void k_agg2(const float* __restrict__ g2, const int* __restrict__ rowptr,
                                              const int* __restrict__ csr, const float* __restrict__ dinv,
                                              const float* __restrict__ b2, float* __restrict__ out, int n) {
    int lane = threadIdx.x & 63;
    int v = blockIdx.x * 4 + (threadIdx.x >> 6);
    if (v >= n) return;
    int beg = rowptr[v], end = rowptr[v + 1];
    int sub = lane >> 4, fl = lane & 15;
    float4 acc = {0.f, 0.f, 0.f, 0.f};
    if (fl < 10) {
        for (int i = beg + sub; i < end; i += 4) {
            int s = csr[i];
            float4 r = *reinterpret_cast<const float4*>(&g2[(size_t)s * 40 + fl * 4]);
            acc.x += r.x; acc.y += r.y; acc.z += r.z; acc.w += r.w;
        }
    }
#pragma unroll
    for (int off = 16; off < 64; off <<= 1) {
        acc.x += __shfl_xor(acc.x, off);
        acc.y += __shfl_xor(acc.y, off);
        acc.z += __shfl_xor(acc.z, off);
        acc.w += __shfl_xor(acc.w, off);
    }
    if (sub == 0 && fl < 10) {
        float4 self = *reinterpret_cast<const float4*>(&g2[(size_t)v * 40 + fl * 4]);
        float4 bb = *reinterpret_cast<const float4*>(&b2[fl * 4]);
        float d = dinv[v];
        float4 o;
        o.x = (acc.x + self.x) * d + bb.x;
        o.y = (acc.y + self.y) * d + bb.y;
        o.z = (acc.z + self.z) * d + bb.z;
        o.w = (acc.w + self.w) * d + bb.w;
        *reinterpret_cast<float4*>(&out[(size_t)v * 40 + fl * 4]) = o;
    }
}

extern "C" void kernel_launch(void* const* d_in, const int* in_sizes, int n_in,
                              void* d_out, int out_size, void* d_ws, size_t ws_size,
                              hipStream_t stream) {
    const float* x  = (const float*)d_in[0];
    const int*   ei = (const int*)d_in[1];
    const float* W1 = (const float*)d_in[2];
    const float* b1 = (const float*)d_in[3];
    const float* W2 = (const float*)d_in[4];
    const float* b2 = (const float*)d_in[5];
    float* out = (float*)d_out;

    int N = in_sizes[0] / 128;   // 100000
    int E = in_sizes[1] / 2;     // 1600000
    const int* src = ei;
    const int* dst = ei + E;

    int NB = (N + NPB - 1) / NPB;      // 391 buckets
    int chunk = (E + NCH - 1) / NCH;   // 6250
    int M = NB * NCH;                  // 100096 (assumes <= 128*SCAN_BLK)
    int nw = (M + SCAN_BLK - 1) / SCAN_BLK;  // 98

    char* w = (char*)d_ws;
    int*   ghist      = (int*)w;           w += (size_t)M * 4;
    int*   gbase      = (int*)w;           w += (size_t)M * 4;
    int*   bucketBase = (int*)w;           w += (size_t)(NB + 1) * 4 + 252;
    int*   wsum       = (int*)w;           w += 128 * 4;
    unsigned int* ebuf = (unsigned int*)w; w += (size_t)E * 4;
    int*   rowptr     = (int*)w;           w += (size_t)(N + 1) * 4 + 252;
    float* dinv       = (float*)w;         w += (size_t)N * 4 + 256;
    int*   csr        = (int*)w;           w += (size_t)E * 4;
    float* g1         = (float*)w;         w += (size_t)N * 64 * 4;
    float* agg1       = (float*)w;         // N*64*4
    float* g2         = g1;                // g1 dead after k_agg1

    k_hist<<<NCH, 256, 0, stream>>>(dst, ghist, E, NB, chunk);
    k_scan_reduce<<<nw, 256, 0, stream>>>(ghist, wsum, M);
    k_scan_mid<<<1, 128, 0, stream>>>(wsum, bucketBase, nw, NB, E);
    k_scan_apply<<<nw, 256, 0, stream>>>(ghist, wsum, gbase, bucketBase, M);
    k_partition<<<NCH, 256, 0, stream>>>(src, dst, gbase, ebuf, E, NB, chunk);
    k_csr<<<NB, 256, 0, stream>>>(ebuf, bucketBase, rowptr, dinv, csr, N, E);

    k_gemm1<<<1024, 256, 0, stream>>>(x, W1, dinv, g1, N);
    k_agg1<<<(N + 3) / 4, 256, 0, stream>>>(g1, rowptr, csr, dinv, agg1, N);
    k_gemm2<<<1024, 256, 0, stream>>>(agg1, W2, b1, dinv, g2, N);
    k_agg2<<<(N + 3) / 4, 256, 0, stream>>>(g2, rowptr, csr, dinv, b2, out, N);
}

// Round 5
// 382.262 us; speedup vs baseline: 1.4507x; 1.0529x over previous
//
#include <hip/hip_runtime.h>

// GCN 2-layer via on-device CSR + gather-aggregation.
// out = A_norm * relu(A_norm * (X W1) + b1) * W2 + b2
// CSR build = two-level counting sort with locality-preserving writes.
// gemm1 = 64x64 WG tile, 4x4 register tile/thread, float4 LDS reads (FMA-bound).

#define NPB 256              // nodes per bucket (pow2, dst>>8)
#define NB_MAX 512           // max buckets supported (N <= 131072)
#define NCH 256              // partition chunks (= WGs)
#define SCAN_BLK 1024        // elements per scan WG

// ---- Pass A: per-chunk bucket histogram -> ghist[b*NCH + w] ----
__global__ __launch_bounds__(256) void k_hist(const int* __restrict__ dst, int* __restrict__ ghist,
                                              int E, int NB, int chunk) {
    __shared__ int h[NB_MAX];
    int tid = threadIdx.x, w = blockIdx.x;
    for (int b = tid; b < NB; b += 256) h[b] = 0;
    __syncthreads();
    int beg = w * chunk, end = min(E, beg + chunk);
    for (int e = beg + tid; e < end; e += 256) atomicAdd(&h[dst[e] >> 8], 1);
    __syncthreads();
    for (int b = tid; b < NB; b += 256) ghist[b * NCH + w] = h[b];
}

// ---- 3-phase exclusive scan of ghist[M] -> gbase[M], bucketBase ----
__global__ __launch_bounds__(256) void k_scan_reduce(const int* __restrict__ ghist, int* __restrict__ wsum, int M) {
    __shared__ int s[256];
    int tid = threadIdx.x;
    int base = blockIdx.x * SCAN_BLK + tid * 4;
    int v = 0;
    if (base + 3 < M) {
        int4 r = *reinterpret_cast<const int4*>(&ghist[base]);
        v = r.x + r.y + r.z + r.w;
    } else {
        for (int j = 0; j < 4; ++j) if (base + j < M) v += ghist[base + j];
    }
    s[tid] = v;
    __syncthreads();
    for (int off = 128; off > 0; off >>= 1) {
        if (tid < off) s[tid] += s[tid + off];
        __syncthreads();
    }
    if (tid == 0) wsum[blockIdx.x] = s[0];
}

// single WG: exclusive-scan nw (<=128) block sums in place; set bucketBase[NB]=E
__global__ __launch_bounds__(128) void k_scan_mid(int* __restrict__ wsum, int* __restrict__ bucketBase,
                                                  int nw, int NB, int E) {
    __shared__ int s[128];
    int tid = threadIdx.x;
    int v = (tid < nw) ? wsum[tid] : 0;
    s[tid] = v;
    __syncthreads();
    for (int off = 1; off < 128; off <<= 1) {
        int add = (tid >= off) ? s[tid - off] : 0;
        __syncthreads();
        s[tid] += add;
        __syncthreads();
    }
    if (tid < nw) wsum[tid] = s[tid] - v;  // exclusive
    if (tid == 0) bucketBase[NB] = E;
}

__global__ __launch_bounds__(256) void k_scan_apply(const int* __restrict__ ghist, const int* __restrict__ wsum,
                                                    int* __restrict__ gbase, int* __restrict__ bucketBase, int M) {
    __shared__ int s[256];
    int tid = threadIdx.x;
    int base = blockIdx.x * SCAN_BLK + tid * 4;
    int e[4];
    int v = 0;
#pragma unroll
    for (int j = 0; j < 4; ++j) {
        int val = (base + j < M) ? ghist[base + j] : 0;
        e[j] = v;  // thread-local exclusive prefix
        v += val;
    }
    s[tid] = v;
    __syncthreads();
    for (int off = 1; off < 256; off <<= 1) {
        int add = (tid >= off) ? s[tid - off] : 0;
        __syncthreads();
        s[tid] += add;
        __syncthreads();
    }
    int tbase = wsum[blockIdx.x] + s[tid] - v;
#pragma unroll
    for (int j = 0; j < 4; ++j) {
        int i = base + j;
        if (i < M) {
            int g = tbase + e[j];
            gbase[i] = g;
            if ((i & (NCH - 1)) == 0) bucketBase[i / NCH] = g;  // first chunk of bucket
        }
    }
}

// ---- Pass B: partition edges into WG-private contiguous runs ----
__global__ __launch_bounds__(256) void k_partition(const int* __restrict__ src, const int* __restrict__ dst,
                                                   const int* __restrict__ gbase, unsigned int* __restrict__ ebuf,
                                                   int E, int NB, int chunk) {
    __shared__ int cur[NB_MAX];
    int tid = threadIdx.x, w = blockIdx.x;
    for (int b = tid; b < NB; b += 256) cur[b] = gbase[b * NCH + w];
    __syncthreads();
    int beg = w * chunk, end = min(E, beg + chunk);
    for (int e = beg + tid; e < end; e += 256) {
        int d = dst[e];
        int b = d >> 8;
        int pos = atomicAdd(&cur[b], 1);
        ebuf[pos] = (unsigned int)src[e] | ((unsigned int)(d & 255) << 24);  // src < 2^24
    }
}

// ---- Pass C: per-bucket counting sort -> rowptr, dinv, csr ----
__global__ __launch_bounds__(256) void k_csr(const unsigned int* __restrict__ ebuf,
                                             const int* __restrict__ bucketBase,
                                             int* __restrict__ rowptr, float* __restrict__ dinv,
                                             int* __restrict__ csr, int n, int E) {
    __shared__ int cnt[NPB];
    __shared__ int sc[NPB];
    __shared__ int cur[NPB];
    int tid = threadIdx.x, b = blockIdx.x;
    int ebeg = bucketBase[b], eend = bucketBase[b + 1];
    cnt[tid] = 0;
    __syncthreads();
    for (int i = ebeg + tid; i < eend; i += 256) atomicAdd(&cnt[ebuf[i] >> 24], 1);
    __syncthreads();
    int v = cnt[tid];
    sc[tid] = v;
    __syncthreads();
    for (int off = 1; off < 256; off <<= 1) {
        int add = (tid >= off) ? sc[tid - off] : 0;
        __syncthreads();
        sc[tid] += add;
        __syncthreads();
    }
    int ex = sc[tid] - v;  // exclusive
    cur[tid] = ex;
    int node = b * NPB + tid;
    if (node < n) {
        rowptr[node] = ebeg + ex;
        dinv[node] = rsqrtf((float)(v + 1));  // +1 self-loop
    }
    if (b == 0 && tid == 0) rowptr[n] = E;
    __syncthreads();
    for (int i = ebeg + tid; i < eend; i += 256) {
        unsigned int word = ebuf[i];
        int pos = atomicAdd(&cur[word >> 24], 1);
        csr[ebeg + pos] = (int)(word & 0xFFFFFFu);
    }
}

// ---- g1[row] = (x[row] @ W1) * dinv[row];  [N,128]@[128,64] ----
// 64x64 tile/WG, 4x4 register tile/thread, k in blocks of 4 via float4 reads.
__global__ __launch_bounds__(256) void k_gemm1(const float* __restrict__ x, const float* __restrict__ W1,
                                               const float* __restrict__ dinv, float* __restrict__ g1,
                                               int n) {
    __shared__ float Ws[128 * 64];   // [k][col], same layout as W1 (32 KB)
    __shared__ float xs[64][132];    // [row][k], +4 pad (33.8 KB)
    int tid = threadIdx.x;
    int tx = tid & 15, ty = tid >> 4;        // col-quad, row-quad
    for (int i = tid; i < 128 * 16; i += 256)
        reinterpret_cast<float4*>(Ws)[i] = reinterpret_cast<const float4*>(W1)[i];

    int ntile = (n + 63) >> 6;
    for (int rg = blockIdx.x; rg < ntile; rg += gridDim.x) {
        int row0 = rg << 6;
        __syncthreads();
        for (int i = tid; i < 64 * 32; i += 256) {
            int r = i >> 5, kq = (i & 31) << 2;
            int row = row0 + r;
            float4 v = {0.f, 0.f, 0.f, 0.f};
            if (row < n) v = *reinterpret_cast<const float4*>(&x[(size_t)row * 128 + kq]);
            *reinterpret_cast<float4*>(&xs[r][kq]) = v;
        }
        __syncthreads();
        float acc[4][4] = {};
#pragma unroll 8
        for (int k = 0; k < 128; k += 4) {
            float xv[4][4], wv[4][4];
#pragma unroll
            for (int i = 0; i < 4; ++i)
                *reinterpret_cast<float4*>(xv[i]) = *reinterpret_cast<const float4*>(&xs[ty * 4 + i][k]);
#pragma unroll
            for (int kk = 0; kk < 4; ++kk)
                *reinterpret_cast<float4*>(wv[kk]) = *reinterpret_cast<const float4*>(&Ws[(k + kk) * 64 + tx * 4]);
#pragma unroll
            for (int kk = 0; kk < 4; ++kk)
#pragma unroll
                for (int i = 0; i < 4; ++i)
#pragma unroll
                    for (int j = 0; j < 4; ++j)
                        acc[i][j] += xv[i][kk] * wv[kk][j];
        }
#pragma unroll
        for (int i = 0; i < 4; ++i) {
            int row = row0 + ty * 4 + i;
            if (row < n) {
                float d = dinv[row];
                float4 o = {acc[i][0] * d, acc[i][1] * d, acc[i][2] * d, acc[i][3] * d};
                *reinterpret_cast<float4*>(&g1[(size_t)row * 64 + tx * 4]) = o;
            }
        }
    }
}

// ---- layer-1 aggregation: agg1[v] = dinv[v]*(g1[v] + sum_{s in N(v)} g1[s]) ----
__global__ __launch_bounds__(256) void k_agg1(const float* __restrict__ g1, const int* __restrict__ rowptr,
                                              const int* __restrict__ csr, const float* __restrict__ dinv,
                                              float* __restrict__ agg1, int n) {
    int lane = threadIdx.x & 63;
    int v = blockIdx.x * 4 + (threadIdx.x >> 6);
    if (v >= n) return;
    int beg = rowptr[v], end = rowptr[v + 1];
    int sub = lane >> 4, fl = lane & 15;
    float4 acc = {0.f, 0.f, 0.f, 0.f};
    for (int i = beg + sub; i < end; i += 4) {
        int s = csr[i];
        float4 r = *reinterpret_cast<const float4*>(&g1[(size_t)s * 64 + fl * 4]);
        acc.x += r.x; acc.y += r.y; acc.z += r.z; acc.w += r.w;
    }
#pragma unroll
    for (int off = 16; off < 64; off <<= 1) {
        acc.x += __shfl_xor(acc.x, off);
        acc.y += __shfl_xor(acc.y, off);
        acc.z += __shfl_xor(acc.z, off);
        acc.w += __shfl_xor(acc.w, off);
    }
    if (sub == 0) {
        float4 self = *reinterpret_cast<const float4*>(&g1[(size_t)v * 64 + fl * 4]);
        float d = dinv[v];
        float4 o;
        o.x = (acc.x + self.x) * d;
        o.y = (acc.y + self.y) * d;
        o.z = (acc.z + self.z) * d;
        o.w = (acc.w + self.w) * d;
        *reinterpret_cast<float4*>(&agg1[(size_t)v * 64 + fl * 4]) = o;
    }
}

// ---- g2[row] = (relu(agg1[row] + b1) @ W2) * dinv[row];  [N,64]@[64,40] ----
__global__ __launch_bounds__(256) void k_gemm2(const float* __restrict__ agg1, const float* __restrict__ W2,
                                               const float* __restrict__ b1, const float* __restrict__ dinv,
                                               float* __restrict__ g2, int n) {
    __shared__ float Ws[64 * 40];
    __shared__ float xs[32][65];
    int tid = threadIdx.x;
    for (int i = tid; i < 64 * 40; i += 256) Ws[i] = W2[i];
    int nrg = n >> 5;
    int r = tid >> 3, cb = (tid & 7) * 5;
    for (int rg = blockIdx.x; rg < nrg; rg += gridDim.x) {
        __syncthreads();
        int row0 = rg << 5;
        for (int i = tid; i < 32 * 64; i += 256) {
            int rr = i >> 6, k = i & 63;
            float vv = agg1[(row0 + rr) * 64 + k] + b1[k];
            xs[rr][k] = vv > 0.f ? vv : 0.f;
        }
        __syncthreads();
        float acc[5] = {0.f, 0.f, 0.f, 0.f, 0.f};
#pragma unroll
        for (int k = 0; k < 64; ++k) {
            float xv = xs[r][k];
#pragma unroll
            for (int j = 0; j < 5; ++j) acc[j] += xv * Ws[k * 40 + cb + j];
        }
        int row = row0 + r;
        float di = dinv[row];
#pragma unroll
        for (int j = 0; j < 5; ++j) g2[row * 40 + cb + j] = acc[j] * di;
    }
}

// ---- layer-2 aggregation + bias: out[v] = dinv[v]*(g2[v] + sum g2[s]) + b2 ----
__global__ __launch_bounds__(256) void k_agg2(const float* __restrict__ g2, const int* __restrict__ rowptr,
                                              const int* __restrict__ csr, const float* __restrict__ dinv,
                                              const float* __restrict__ b2, float* __restrict__ out, int n) {
    int lane = threadIdx.x & 63;
    int v = blockIdx.x * 4 + (threadIdx.x >> 6);
    if (v >= n) return;
    int beg = rowptr[v], end = rowptr[v + 1];
    int sub = lane >> 4, fl = lane & 15;
    float4 acc = {0.f, 0.f, 0.f, 0.f};
    if (fl < 10) {
        for (int i = beg + sub; i < end; i += 4) {
            int s = csr[i];
            float4 r = *reinterpret_cast<const float4*>(&g2[(size_t)s * 40 + fl * 4]);
            acc.x += r.x; acc.y += r.y; acc.z += r.z; acc.w += r.w;
        }
    }
#pragma unroll
    for (int off = 16; off < 64; off <<= 1) {
        acc.x += __shfl_xor(acc.x, off);
        acc.y += __shfl_xor(acc.y, off);
        acc.z += __shfl_xor(acc.z, off);
        acc.w += __shfl_xor(acc.w, off);
    }
    if (sub == 0 && fl < 10) {
        float4 self = *reinterpret_cast<const float4*>(&g2[(size_t)v * 40 + fl * 4]);
        float4 bb = *reinterpret_cast<const float4*>(&b2[fl * 4]);
        float d = dinv[v];
        float4 o;
        o.x = (acc.x + self.x) * d + bb.x;
        o.y = (acc.y + self.y) * d + bb.y;
        o.z = (acc.z + self.z) * d + bb.z;
        o.w = (acc.w + self.w) * d + bb.w;
        *reinterpret_cast<float4*>(&out[(size_t)v * 40 + fl * 4]) = o;
    }
}

extern "C" void kernel_launch(void* const* d_in, const int* in_sizes, int n_in,
                              void* d_out, int out_size, void* d_ws, size_t ws_size,
                              hipStream_t stream) {
    const float* x  = (const float*)d_in[0];
    const int*   ei = (const int*)d_in[1];
    const float* W1 = (const float*)d_in[2];
    const float* b1 = (const float*)d_in[3];
    const float* W2 = (const float*)d_in[4];
    const float* b2 = (const float*)d_in[5];
    float* out = (float*)d_out;

    int N = in_sizes[0] / 128;   // 100000
    int E = in_sizes[1] / 2;     // 1600000
    const int* src = ei;
    const int* dst = ei + E;

    int NB = (N + NPB - 1) / NPB;      // 391 buckets
    int chunk = (E + NCH - 1) / NCH;   // 6250
    int M = NB * NCH;                  // 100096 (assumes <= 128*SCAN_BLK)
    int nw = (M + SCAN_BLK - 1) / SCAN_BLK;  // 98

    char* w = (char*)d_ws;
    int*   ghist      = (int*)w;           w += (size_t)M * 4;
    int*   gbase      = (int*)w;           w += (size_t)M * 4;
    int*   bucketBase = (int*)w;           w += (size_t)(NB + 1) * 4 + 252;
    int*   wsum       = (int*)w;           w += 128 * 4;
    unsigned int* ebuf = (unsigned int*)w; w += (size_t)E * 4;
    int*   rowptr     = (int*)w;           w += (size_t)(N + 1) * 4 + 252;
    float* dinv       = (float*)w;         w += (size_t)N * 4 + 256;
    int*   csr        = (int*)w;           w += (size_t)E * 4;
    float* g1         = (float*)w;         w += (size_t)N * 64 * 4;
    float* agg1       = (float*)w;         // N*64*4
    float* g2         = g1;                // g1 dead after k_agg1

    k_hist<<<NCH, 256, 0, stream>>>(dst, ghist, E, NB, chunk);
    k_scan_reduce<<<nw, 256, 0, stream>>>(ghist, wsum, M);
    k_scan_mid<<<1, 128, 0, stream>>>(wsum, bucketBase, nw, NB, E);
    k_scan_apply<<<nw, 256, 0, stream>>>(ghist, wsum, gbase, bucketBase, M);
    k_partition<<<NCH, 256, 0, stream>>>(src, dst, gbase, ebuf, E, NB, chunk);
    k_csr<<<NB, 256, 0, stream>>>(ebuf, bucketBase, rowptr, dinv, csr, N, E);

    int ntile = (N + 63) >> 6;   // 1563
    k_gemm1<<<ntile, 256, 0, stream>>>(x, W1, dinv, g1, N);
    k_agg1<<<(N + 3) / 4, 256, 0, stream>>>(g1, rowptr, csr, dinv, agg1, N);
    k_gemm2<<<1024, 256, 0, stream>>>(agg1, W2, b1, dinv, g2, N);
    k_agg2<<<(N + 3) / 4, 256, 0, stream>>>(g2, rowptr, csr, dinv, b2, out, N);
}

// Round 6
// 363.304 us; speedup vs baseline: 1.5264x; 1.0522x over previous
//
#include <hip/hip_runtime.h>
#include <hip/hip_fp16.h>

// GCN 2-layer via on-device CSR + gather-aggregation.
// out = A_norm * relu(A_norm * (X W1) + b1) * W2 + b2
// CSR build = two-level counting sort with locality-preserving writes.
// Gather buffers g1/g2 stored fp16 (halves random-gather HBM traffic);
// all accumulation in fp32.

#define NPB 256              // nodes per bucket (pow2, dst>>8)
#define NB_MAX 512           // max buckets supported (N <= 131072)
#define NCH 256              // partition chunks (= WGs)
#define SCAN_BLK 1024        // elements per scan WG

// ---- Pass A: per-chunk bucket histogram -> ghist[b*NCH + w] ----
__global__ __launch_bounds__(256) void k_hist(const int* __restrict__ dst, int* __restrict__ ghist,
                                              int E, int NB, int chunk) {
    __shared__ int h[NB_MAX];
    int tid = threadIdx.x, w = blockIdx.x;
    for (int b = tid; b < NB; b += 256) h[b] = 0;
    __syncthreads();
    int beg = w * chunk, end = min(E, beg + chunk);
    for (int e = beg + tid; e < end; e += 256) atomicAdd(&h[dst[e] >> 8], 1);
    __syncthreads();
    for (int b = tid; b < NB; b += 256) ghist[b * NCH + w] = h[b];
}

// ---- 3-phase exclusive scan of ghist[M] -> gbase[M], bucketBase ----
__global__ __launch_bounds__(256) void k_scan_reduce(const int* __restrict__ ghist, int* __restrict__ wsum, int M) {
    __shared__ int s[256];
    int tid = threadIdx.x;
    int base = blockIdx.x * SCAN_BLK + tid * 4;
    int v = 0;
    if (base + 3 < M) {
        int4 r = *reinterpret_cast<const int4*>(&ghist[base]);
        v = r.x + r.y + r.z + r.w;
    } else {
        for (int j = 0; j < 4; ++j) if (base + j < M) v += ghist[base + j];
    }
    s[tid] = v;
    __syncthreads();
    for (int off = 128; off > 0; off >>= 1) {
        if (tid < off) s[tid] += s[tid + off];
        __syncthreads();
    }
    if (tid == 0) wsum[blockIdx.x] = s[0];
}

// single WG: exclusive-scan nw (<=128) block sums in place; set bucketBase[NB]=E
__global__ __launch_bounds__(128) void k_scan_mid(int* __restrict__ wsum, int* __restrict__ bucketBase,
                                                  int nw, int NB, int E) {
    __shared__ int s[128];
    int tid = threadIdx.x;
    int v = (tid < nw) ? wsum[tid] : 0;
    s[tid] = v;
    __syncthreads();
    for (int off = 1; off < 128; off <<= 1) {
        int add = (tid >= off) ? s[tid - off] : 0;
        __syncthreads();
        s[tid] += add;
        __syncthreads();
    }
    if (tid < nw) wsum[tid] = s[tid] - v;  // exclusive
    if (tid == 0) bucketBase[NB] = E;
}

__global__ __launch_bounds__(256) void k_scan_apply(const int* __restrict__ ghist, const int* __restrict__ wsum,
                                                    int* __restrict__ gbase, int* __restrict__ bucketBase, int M) {
    __shared__ int s[256];
    int tid = threadIdx.x;
    int base = blockIdx.x * SCAN_BLK + tid * 4;
    int e[4];
    int v = 0;
#pragma unroll
    for (int j = 0; j < 4; ++j) {
        int val = (base + j < M) ? ghist[base + j] : 0;
        e[j] = v;  // thread-local exclusive prefix
        v += val;
    }
    s[tid] = v;
    __syncthreads();
    for (int off = 1; off < 256; off <<= 1) {
        int add = (tid >= off) ? s[tid - off] : 0;
        __syncthreads();
        s[tid] += add;
        __syncthreads();
    }
    int tbase = wsum[blockIdx.x] + s[tid] - v;
#pragma unroll
    for (int j = 0; j < 4; ++j) {
        int i = base + j;
        if (i < M) {
            int g = tbase + e[j];
            gbase[i] = g;
            if ((i & (NCH - 1)) == 0) bucketBase[i / NCH] = g;  // first chunk of bucket
        }
    }
}

// ---- Pass B: partition edges into WG-private contiguous runs ----
__global__ __launch_bounds__(256) void k_partition(const int* __restrict__ src, const int* __restrict__ dst,
                                                   const int* __restrict__ gbase, unsigned int* __restrict__ ebuf,
                                                   int E, int NB, int chunk) {
    __shared__ int cur[NB_MAX];
    int tid = threadIdx.x, w = blockIdx.x;
    for (int b = tid; b < NB; b += 256) cur[b] = gbase[b * NCH + w];
    __syncthreads();
    int beg = w * chunk, end = min(E, beg + chunk);
    for (int e = beg + tid; e < end; e += 256) {
        int d = dst[e];
        int b = d >> 8;
        int pos = atomicAdd(&cur[b], 1);
        ebuf[pos] = (unsigned int)src[e] | ((unsigned int)(d & 255) << 24);  // src < 2^24
    }
}

// ---- Pass C: per-bucket counting sort -> rowptr, dinv, csr ----
__global__ __launch_bounds__(256) void k_csr(const unsigned int* __restrict__ ebuf,
                                             const int* __restrict__ bucketBase,
                                             int* __restrict__ rowptr, float* __restrict__ dinv,
                                             int* __restrict__ csr, int n, int E) {
    __shared__ int cnt[NPB];
    __shared__ int sc[NPB];
    __shared__ int cur[NPB];
    int tid = threadIdx.x, b = blockIdx.x;
    int ebeg = bucketBase[b], eend = bucketBase[b + 1];
    cnt[tid] = 0;
    __syncthreads();
    for (int i = ebeg + tid; i < eend; i += 256) atomicAdd(&cnt[ebuf[i] >> 24], 1);
    __syncthreads();
    int v = cnt[tid];
    sc[tid] = v;
    __syncthreads();
    for (int off = 1; off < 256; off <<= 1) {
        int add = (tid >= off) ? sc[tid - off] : 0;
        __syncthreads();
        sc[tid] += add;
        __syncthreads();
    }
    int ex = sc[tid] - v;  // exclusive
    cur[tid] = ex;
    int node = b * NPB + tid;
    if (node < n) {
        rowptr[node] = ebeg + ex;
        dinv[node] = rsqrtf((float)(v + 1));  // +1 self-loop
    }
    if (b == 0 && tid == 0) rowptr[n] = E;
    __syncthreads();
    for (int i = ebeg + tid; i < eend; i += 256) {
        unsigned int word = ebuf[i];
        int pos = atomicAdd(&cur[word >> 24], 1);
        csr[ebeg + pos] = (int)(word & 0xFFFFFFu);
    }
}

// ---- g1[row] = fp16( (x[row] @ W1) * dinv[row] );  [N,128]@[128,64] ----
// 64x64 tile/WG, 4x4 register tile/thread, k in blocks of 4 via float4 reads.
__global__ __launch_bounds__(256) void k_gemm1(const float* __restrict__ x, const float* __restrict__ W1,
                                               const float* __restrict__ dinv, __half* __restrict__ g1,
                                               int n) {
    __shared__ float Ws[128 * 64];   // [k][col], same layout as W1 (32 KB)
    __shared__ float xs[64][132];    // [row][k], +4 pad (33.8 KB)
    int tid = threadIdx.x;
    int tx = tid & 15, ty = tid >> 4;        // col-quad, row-quad
    for (int i = tid; i < 128 * 16; i += 256)
        reinterpret_cast<float4*>(Ws)[i] = reinterpret_cast<const float4*>(W1)[i];

    int ntile = (n + 63) >> 6;
    for (int rg = blockIdx.x; rg < ntile; rg += gridDim.x) {
        int row0 = rg << 6;
        __syncthreads();
        for (int i = tid; i < 64 * 32; i += 256) {
            int r = i >> 5, kq = (i & 31) << 2;
            int row = row0 + r;
            float4 v = {0.f, 0.f, 0.f, 0.f};
            if (row < n) v = *reinterpret_cast<const float4*>(&x[(size_t)row * 128 + kq]);
            *reinterpret_cast<float4*>(&xs[r][kq]) = v;
        }
        __syncthreads();
        float acc[4][4] = {};
#pragma unroll 8
        for (int k = 0; k < 128; k += 4) {
            float xv[4][4], wv[4][4];
#pragma unroll
            for (int i = 0; i < 4; ++i)
                *reinterpret_cast<float4*>(xv[i]) = *reinterpret_cast<const float4*>(&xs[ty * 4 + i][k]);
#pragma unroll
            for (int kk = 0; kk < 4; ++kk)
                *reinterpret_cast<float4*>(wv[kk]) = *reinterpret_cast<const float4*>(&Ws[(k + kk) * 64 + tx * 4]);
#pragma unroll
            for (int kk = 0; kk < 4; ++kk)
#pragma unroll
                for (int i = 0; i < 4; ++i)
#pragma unroll
                    for (int j = 0; j < 4; ++j)
                        acc[i][j] += xv[i][kk] * wv[kk][j];
        }
#pragma unroll
        for (int i = 0; i < 4; ++i) {
            int row = row0 + ty * 4 + i;
            if (row < n) {
                float d = dinv[row];
                __half2 p0 = __halves2half2(__float2half_rn(acc[i][0] * d), __float2half_rn(acc[i][1] * d));
                __half2 p1 = __halves2half2(__float2half_rn(acc[i][2] * d), __float2half_rn(acc[i][3] * d));
                uint2 wq;
                wq.x = *reinterpret_cast<unsigned*>(&p0);
                wq.y = *reinterpret_cast<unsigned*>(&p1);
                *reinterpret_cast<uint2*>(&g1[(size_t)row * 64 + tx * 4]) = wq;
            }
        }
    }
}

__device__ __forceinline__ void acc_half4(float4& acc, uint2 r) {
    __half2 h0 = *reinterpret_cast<__half2*>(&r.x);
    __half2 h1 = *reinterpret_cast<__half2*>(&r.y);
    float2 f0 = __half22float2(h0);
    float2 f1 = __half22float2(h1);
    acc.x += f0.x; acc.y += f0.y; acc.z += f1.x; acc.w += f1.y;
}

// ---- layer-1 aggregation: agg1[v] = dinv[v]*(g1[v] + sum_{s in N(v)} g1[s]) ----
// one wave per node; 4 edge slots x 16 lanes x 4 halves (8 B) = 128 B/edge
__global__ __launch_bounds__(256) void k_agg1(const __half* __restrict__ g1, const int* __restrict__ rowptr,
                                              const int* __restrict__ csr, const float* __restrict__ dinv,
                                              float* __restrict__ agg1, int n) {
    int lane = threadIdx.x & 63;
    int v = blockIdx.x * 4 + (threadIdx.x >> 6);
    if (v >= n) return;
    int beg = rowptr[v], end = rowptr[v + 1];
    int sub = lane >> 4, fl = lane & 15;
    float4 acc = {0.f, 0.f, 0.f, 0.f};
    for (int i = beg + sub; i < end; i += 4) {
        int s = csr[i];
        acc_half4(acc, *reinterpret_cast<const uint2*>(&g1[(size_t)s * 64 + fl * 4]));
    }
#pragma unroll
    for (int off = 16; off < 64; off <<= 1) {
        acc.x += __shfl_xor(acc.x, off);
        acc.y += __shfl_xor(acc.y, off);
        acc.z += __shfl_xor(acc.z, off);
        acc.w += __shfl_xor(acc.w, off);
    }
    if (sub == 0) {
        float4 self = {0.f, 0.f, 0.f, 0.f};
        acc_half4(self, *reinterpret_cast<const uint2*>(&g1[(size_t)v * 64 + fl * 4]));
        float d = dinv[v];
        float4 o;
        o.x = (acc.x + self.x) * d;
        o.y = (acc.y + self.y) * d;
        o.z = (acc.z + self.z) * d;
        o.w = (acc.w + self.w) * d;
        *reinterpret_cast<float4*>(&agg1[(size_t)v * 64 + fl * 4]) = o;
    }
}

// ---- g2[row] = fp16( (relu(agg1[row] + b1) @ W2) * dinv[row] );  [N,64]@[64,40] ----
__global__ __launch_bounds__(256) void k_gemm2(const float* __restrict__ agg1, const float* __restrict__ W2,
                                               const float* __restrict__ b1, const float* __restrict__ dinv,
                                               __half* __restrict__ g2, int n) {
    __shared__ float Ws[64 * 40];
    __shared__ float xs[32][65];
    int tid = threadIdx.x;
    for (int i = tid; i < 64 * 40; i += 256) Ws[i] = W2[i];
    int nrg = n >> 5;
    int r = tid >> 3, cb = (tid & 7) * 5;
    for (int rg = blockIdx.x; rg < nrg; rg += gridDim.x) {
        __syncthreads();
        int row0 = rg << 5;
        for (int i = tid; i < 32 * 64; i += 256) {
            int rr = i >> 6, k = i & 63;
            float vv = agg1[(row0 + rr) * 64 + k] + b1[k];
            xs[rr][k] = vv > 0.f ? vv : 0.f;
        }
        __syncthreads();
        float acc[5] = {0.f, 0.f, 0.f, 0.f, 0.f};
#pragma unroll
        for (int k = 0; k < 64; ++k) {
            float xv = xs[r][k];
#pragma unroll
            for (int j = 0; j < 5; ++j) acc[j] += xv * Ws[k * 40 + cb + j];
        }
        int row = row0 + r;
        float di = dinv[row];
#pragma unroll
        for (int j = 0; j < 5; ++j) g2[(size_t)row * 40 + cb + j] = __float2half_rn(acc[j] * di);
    }
}

// ---- layer-2 aggregation + bias: out[v] = dinv[v]*(g2[v] + sum g2[s]) + b2 ----
// 40 halves = 80 B/edge: 10 lanes x 4 halves (8 B)
__global__ __launch_bounds__(256) void k_agg2(const __half* __restrict__ g2, const int* __restrict__ rowptr,
                                              const int* __restrict__ csr, const float* __restrict__ dinv,
                                              const float* __restrict__ b2, float* __restrict__ out, int n) {
    int lane = threadIdx.x & 63;
    int v = blockIdx.x * 4 + (threadIdx.x >> 6);
    if (v >= n) return;
    int beg = rowptr[v], end = rowptr[v + 1];
    int sub = lane >> 4, fl = lane & 15;
    float4 acc = {0.f, 0.f, 0.f, 0.f};
    if (fl < 10) {
        for (int i = beg + sub; i < end; i += 4) {
            int s = csr[i];
            acc_half4(acc, *reinterpret_cast<const uint2*>(&g2[(size_t)s * 40 + fl * 4]));
        }
    }
#pragma unroll
    for (int off = 16; off < 64; off <<= 1) {
        acc.x += __shfl_xor(acc.x, off);
        acc.y += __shfl_xor(acc.y, off);
        acc.z += __shfl_xor(acc.z, off);
        acc.w += __shfl_xor(acc.w, off);
    }
    if (sub == 0 && fl < 10) {
        float4 self = {0.f, 0.f, 0.f, 0.f};
        acc_half4(self, *reinterpret_cast<const uint2*>(&g2[(size_t)v * 40 + fl * 4]));
        float4 bb = *reinterpret_cast<const float4*>(&b2[fl * 4]);
        float d = dinv[v];
        float4 o;
        o.x = (acc.x + self.x) * d + bb.x;
        o.y = (acc.y + self.y) * d + bb.y;
        o.z = (acc.z + self.z) * d + bb.z;
        o.w = (acc.w + self.w) * d + bb.w;
        *reinterpret_cast<float4*>(&out[(size_t)v * 40 + fl * 4]) = o;
    }
}

extern "C" void kernel_launch(void* const* d_in, const int* in_sizes, int n_in,
                              void* d_out, int out_size, void* d_ws, size_t ws_size,
                              hipStream_t stream) {
    const float* x  = (const float*)d_in[0];
    const int*   ei = (const int*)d_in[1];
    const float* W1 = (const float*)d_in[2];
    const float* b1 = (const float*)d_in[3];
    const float* W2 = (const float*)d_in[4];
    const float* b2 = (const float*)d_in[5];
    float* out = (float*)d_out;

    int N = in_sizes[0] / 128;   // 100000
    int E = in_sizes[1] / 2;     // 1600000
    const int* src = ei;
    const int* dst = ei + E;

    int NB = (N + NPB - 1) / NPB;      // 391 buckets
    int chunk = (E + NCH - 1) / NCH;   // 6250
    int M = NB * NCH;                  // 100096 (assumes <= 128*SCAN_BLK)
    int nw = (M + SCAN_BLK - 1) / SCAN_BLK;  // 98

    char* w = (char*)d_ws;
    int*   ghist      = (int*)w;           w += (size_t)M * 4;
    int*   gbase      = (int*)w;           w += (size_t)M * 4;
    int*   bucketBase = (int*)w;           w += (size_t)(NB + 1) * 4 + 252;
    int*   wsum       = (int*)w;           w += 128 * 4;
    unsigned int* ebuf = (unsigned int*)w; w += (size_t)E * 4;
    int*   rowptr     = (int*)w;           w += (size_t)(N + 1) * 4 + 252;
    float* dinv       = (float*)w;         w += (size_t)N * 4 + 256;
    int*   csr        = (int*)w;           w += (size_t)E * 4;
    __half* g1        = (__half*)w;        w += (size_t)N * 64 * 2;
    float* agg1       = (float*)w;         w += (size_t)N * 64 * 4;
    __half* g2        = (__half*)w;        // N*40*2

    k_hist<<<NCH, 256, 0, stream>>>(dst, ghist, E, NB, chunk);
    k_scan_reduce<<<nw, 256, 0, stream>>>(ghist, wsum, M);
    k_scan_mid<<<1, 128, 0, stream>>>(wsum, bucketBase, nw, NB, E);
    k_scan_apply<<<nw, 256, 0, stream>>>(ghist, wsum, gbase, bucketBase, M);
    k_partition<<<NCH, 256, 0, stream>>>(src, dst, gbase, ebuf, E, NB, chunk);
    k_csr<<<NB, 256, 0, stream>>>(ebuf, bucketBase, rowptr, dinv, csr, N, E);

    int ntile = (N + 63) >> 6;   // 1563
    k_gemm1<<<ntile, 256, 0, stream>>>(x, W1, dinv, g1, N);
    k_agg1<<<(N + 3) / 4, 256, 0, stream>>>(g1, rowptr, csr, dinv, agg1, N);
    k_gemm2<<<1024, 256, 0, stream>>>(agg1, W2, b1, dinv, g2, N);
    k_agg2<<<(N + 3) / 4, 256, 0, stream>>>(g2, rowptr, csr, dinv, b2, out, N);
}

// Round 7
// 347.220 us; speedup vs baseline: 1.5971x; 1.0463x over previous
//
#include <hip/hip_runtime.h>
#include <hip/hip_fp16.h>

// GCN 2-layer via on-device CSR + gather-aggregation.
// out = A_norm * relu(A_norm * (X W1) + b1) * W2 + b2
// CSR build = two-level counting sort with locality-preserving writes.
// Gather buffers g1/g2 stored fp16 (halves random-gather HBM traffic);
// all accumulation in fp32.
// gemm1: Ws-only LDS (32KB -> 5 WG/CU); x read direct from global (L1 broadcast).

#define NPB 256              // nodes per bucket (pow2, dst>>8)
#define NB_MAX 512           // max buckets supported (N <= 131072)
#define NCH 256              // partition chunks (= WGs)
#define SCAN_BLK 1024        // elements per scan WG

// ---- Pass A: per-chunk bucket histogram -> ghist[b*NCH + w] ----
__global__ __launch_bounds__(256) void k_hist(const int* __restrict__ dst, int* __restrict__ ghist,
                                              int E, int NB, int chunk) {
    __shared__ int h[NB_MAX];
    int tid = threadIdx.x, w = blockIdx.x;
    for (int b = tid; b < NB; b += 256) h[b] = 0;
    __syncthreads();
    int beg = w * chunk, end = min(E, beg + chunk);
    for (int e = beg + tid; e < end; e += 256) atomicAdd(&h[dst[e] >> 8], 1);
    __syncthreads();
    for (int b = tid; b < NB; b += 256) ghist[b * NCH + w] = h[b];
}

// ---- 3-phase exclusive scan of ghist[M] -> gbase[M], bucketBase ----
__global__ __launch_bounds__(256) void k_scan_reduce(const int* __restrict__ ghist, int* __restrict__ wsum, int M) {
    __shared__ int s[256];
    int tid = threadIdx.x;
    int base = blockIdx.x * SCAN_BLK + tid * 4;
    int v = 0;
    if (base + 3 < M) {
        int4 r = *reinterpret_cast<const int4*>(&ghist[base]);
        v = r.x + r.y + r.z + r.w;
    } else {
        for (int j = 0; j < 4; ++j) if (base + j < M) v += ghist[base + j];
    }
    s[tid] = v;
    __syncthreads();
    for (int off = 128; off > 0; off >>= 1) {
        if (tid < off) s[tid] += s[tid + off];
        __syncthreads();
    }
    if (tid == 0) wsum[blockIdx.x] = s[0];
}

// single WG: exclusive-scan nw (<=128) block sums in place; set bucketBase[NB]=E
__global__ __launch_bounds__(128) void k_scan_mid(int* __restrict__ wsum, int* __restrict__ bucketBase,
                                                  int nw, int NB, int E) {
    __shared__ int s[128];
    int tid = threadIdx.x;
    int v = (tid < nw) ? wsum[tid] : 0;
    s[tid] = v;
    __syncthreads();
    for (int off = 1; off < 128; off <<= 1) {
        int add = (tid >= off) ? s[tid - off] : 0;
        __syncthreads();
        s[tid] += add;
        __syncthreads();
    }
    if (tid < nw) wsum[tid] = s[tid] - v;  // exclusive
    if (tid == 0) bucketBase[NB] = E;
}

__global__ __launch_bounds__(256) void k_scan_apply(const int* __restrict__ ghist, const int* __restrict__ wsum,
                                                    int* __restrict__ gbase, int* __restrict__ bucketBase, int M) {
    __shared__ int s[256];
    int tid = threadIdx.x;
    int base = blockIdx.x * SCAN_BLK + tid * 4;
    int e[4];
    int v = 0;
#pragma unroll
    for (int j = 0; j < 4; ++j) {
        int val = (base + j < M) ? ghist[base + j] : 0;
        e[j] = v;  // thread-local exclusive prefix
        v += val;
    }
    s[tid] = v;
    __syncthreads();
    for (int off = 1; off < 256; off <<= 1) {
        int add = (tid >= off) ? s[tid - off] : 0;
        __syncthreads();
        s[tid] += add;
        __syncthreads();
    }
    int tbase = wsum[blockIdx.x] + s[tid] - v;
#pragma unroll
    for (int j = 0; j < 4; ++j) {
        int i = base + j;
        if (i < M) {
            int g = tbase + e[j];
            gbase[i] = g;
            if ((i & (NCH - 1)) == 0) bucketBase[i / NCH] = g;  // first chunk of bucket
        }
    }
}

// ---- Pass B: partition edges into WG-private contiguous runs ----
__global__ __launch_bounds__(256) void k_partition(const int* __restrict__ src, const int* __restrict__ dst,
                                                   const int* __restrict__ gbase, unsigned int* __restrict__ ebuf,
                                                   int E, int NB, int chunk) {
    __shared__ int cur[NB_MAX];
    int tid = threadIdx.x, w = blockIdx.x;
    for (int b = tid; b < NB; b += 256) cur[b] = gbase[b * NCH + w];
    __syncthreads();
    int beg = w * chunk, end = min(E, beg + chunk);
    for (int e = beg + tid; e < end; e += 256) {
        int d = dst[e];
        int b = d >> 8;
        int pos = atomicAdd(&cur[b], 1);
        ebuf[pos] = (unsigned int)src[e] | ((unsigned int)(d & 255) << 24);  // src < 2^24
    }
}

// ---- Pass C: per-bucket counting sort -> rowptr, dinv, csr ----
__global__ __launch_bounds__(256) void k_csr(const unsigned int* __restrict__ ebuf,
                                             const int* __restrict__ bucketBase,
                                             int* __restrict__ rowptr, float* __restrict__ dinv,
                                             int* __restrict__ csr, int n, int E) {
    __shared__ int cnt[NPB];
    __shared__ int sc[NPB];
    __shared__ int cur[NPB];
    int tid = threadIdx.x, b = blockIdx.x;
    int ebeg = bucketBase[b], eend = bucketBase[b + 1];
    cnt[tid] = 0;
    __syncthreads();
    for (int i = ebeg + tid; i < eend; i += 256) atomicAdd(&cnt[ebuf[i] >> 24], 1);
    __syncthreads();
    int v = cnt[tid];
    sc[tid] = v;
    __syncthreads();
    for (int off = 1; off < 256; off <<= 1) {
        int add = (tid >= off) ? sc[tid - off] : 0;
        __syncthreads();
        sc[tid] += add;
        __syncthreads();
    }
    int ex = sc[tid] - v;  // exclusive
    cur[tid] = ex;
    int node = b * NPB + tid;
    if (node < n) {
        rowptr[node] = ebeg + ex;
        dinv[node] = rsqrtf((float)(v + 1));  // +1 self-loop
    }
    if (b == 0 && tid == 0) rowptr[n] = E;
    __syncthreads();
    for (int i = ebeg + tid; i < eend; i += 256) {
        unsigned int word = ebuf[i];
        int pos = atomicAdd(&cur[word >> 24], 1);
        csr[ebeg + pos] = (int)(word & 0xFFFFFFu);
    }
}

// ---- g1[row] = fp16( (x[row] @ W1) * dinv[row] );  [N,128]@[128,64] ----
// 64x64 tile/WG, 4x4 register tile/thread. Ws-only LDS (32 KB); x rows read
// directly from global (same-address lanes dedup'd by coalescer, L1/L2-hit).
__global__ __launch_bounds__(256) void k_gemm1(const float* __restrict__ x, const float* __restrict__ W1,
                                               const float* __restrict__ dinv, __half* __restrict__ g1,
                                               int n) {
    __shared__ float Ws[128 * 64];   // [k][col], same layout as W1 (32 KB)
    int tid = threadIdx.x;
    int tx = tid & 15, ty = tid >> 4;        // col-quad, row-quad
    for (int i = tid; i < 128 * 16; i += 256)
        reinterpret_cast<float4*>(Ws)[i] = reinterpret_cast<const float4*>(W1)[i];
    __syncthreads();

    int ntile = (n + 63) >> 6;
    for (int rg = blockIdx.x; rg < ntile; rg += gridDim.x) {
        int row0 = rg << 6;
        int r0 = row0 + ty * 4;
        const float* xp0 = x + (size_t)r0 * 128;
        bool full = (r0 + 3) < n;
        float acc[4][4] = {};
#pragma unroll 4
        for (int k = 0; k < 128; k += 4) {
            float xv[4][4], wv[4][4];
            if (full) {
#pragma unroll
                for (int i = 0; i < 4; ++i)
                    *reinterpret_cast<float4*>(xv[i]) = *reinterpret_cast<const float4*>(&xp0[(size_t)i * 128 + k]);
            } else {
#pragma unroll
                for (int i = 0; i < 4; ++i) {
                    float4 v = {0.f, 0.f, 0.f, 0.f};
                    if (r0 + i < n) v = *reinterpret_cast<const float4*>(&xp0[(size_t)i * 128 + k]);
                    *reinterpret_cast<float4*>(xv[i]) = v;
                }
            }
#pragma unroll
            for (int kk = 0; kk < 4; ++kk)
                *reinterpret_cast<float4*>(wv[kk]) = *reinterpret_cast<const float4*>(&Ws[(k + kk) * 64 + tx * 4]);
#pragma unroll
            for (int kk = 0; kk < 4; ++kk)
#pragma unroll
                for (int i = 0; i < 4; ++i)
#pragma unroll
                    for (int j = 0; j < 4; ++j)
                        acc[i][j] += xv[i][kk] * wv[kk][j];
        }
#pragma unroll
        for (int i = 0; i < 4; ++i) {
            int row = r0 + i;
            if (row < n) {
                float d = dinv[row];
                __half2 p0 = __halves2half2(__float2half_rn(acc[i][0] * d), __float2half_rn(acc[i][1] * d));
                __half2 p1 = __halves2half2(__float2half_rn(acc[i][2] * d), __float2half_rn(acc[i][3] * d));
                uint2 wq;
                wq.x = *reinterpret_cast<unsigned*>(&p0);
                wq.y = *reinterpret_cast<unsigned*>(&p1);
                *reinterpret_cast<uint2*>(&g1[(size_t)row * 64 + tx * 4]) = wq;
            }
        }
    }
}

__device__ __forceinline__ void acc_half4(float4& acc, uint2 r) {
    __half2 h0 = *reinterpret_cast<__half2*>(&r.x);
    __half2 h1 = *reinterpret_cast<__half2*>(&r.y);
    float2 f0 = __half22float2(h0);
    float2 f1 = __half22float2(h1);
    acc.x += f0.x; acc.y += f0.y; acc.z += f1.x; acc.w += f1.y;
}

// ---- layer-1 aggregation: agg1[v] = dinv[v]*(g1[v] + sum_{s in N(v)} g1[s]) ----
// one wave per node; 4 edge slots x 16 lanes x 4 halves (8 B) = 128 B/edge
__global__ __launch_bounds__(256) void k_agg1(const __half* __restrict__ g1, const int* __restrict__ rowptr,
                                              const int* __restrict__ csr, const float* __restrict__ dinv,
                                              float* __restrict__ agg1, int n) {
    int lane = threadIdx.x & 63;
    int v = blockIdx.x * 4 + (threadIdx.x >> 6);
    if (v >= n) return;
    int beg = rowptr[v], end = rowptr[v + 1];
    int sub = lane >> 4, fl = lane & 15;
    float4 acc = {0.f, 0.f, 0.f, 0.f};
    for (int i = beg + sub; i < end; i += 4) {
        int s = csr[i];
        acc_half4(acc, *reinterpret_cast<const uint2*>(&g1[(size_t)s * 64 + fl * 4]));
    }
#pragma unroll
    for (int off = 16; off < 64; off <<= 1) {
        acc.x += __shfl_xor(acc.x, off);
        acc.y += __shfl_xor(acc.y, off);
        acc.z += __shfl_xor(acc.z, off);
        acc.w += __shfl_xor(acc.w, off);
    }
    if (sub == 0) {
        float4 self = {0.f, 0.f, 0.f, 0.f};
        acc_half4(self, *reinterpret_cast<const uint2*>(&g1[(size_t)v * 64 + fl * 4]));
        float d = dinv[v];
        float4 o;
        o.x = (acc.x + self.x) * d;
        o.y = (acc.y + self.y) * d;
        o.z = (acc.z + self.z) * d;
        o.w = (acc.w + self.w) * d;
        *reinterpret_cast<float4*>(&agg1[(size_t)v * 64 + fl * 4]) = o;
    }
}

// ---- g2[row] = fp16( (relu(agg1[row] + b1) @ W2) * dinv[row] );  [N,64]@[64,40] ----
__global__ __launch_bounds__(256) void k_gemm2(const float* __restrict__ agg1, const float* __restrict__ W2,
                                               const float* __restrict__ b1, const float* __restrict__ dinv,
                                               __half* __restrict__ g2, int n) {
    __shared__ float Ws[64 * 40];
    __shared__ float xs[32][65];
    int tid = threadIdx.x;
    for (int i = tid; i < 64 * 40; i += 256) Ws[i] = W2[i];
    int nrg = n >> 5;
    int r = tid >> 3, cb = (tid & 7) * 5;
    for (int rg = blockIdx.x; rg < nrg; rg += gridDim.x) {
        __syncthreads();
        int row0 = rg << 5;
        for (int i = tid; i < 32 * 64; i += 256) {
            int rr = i >> 6, k = i & 63;
            float vv = agg1[(row0 + rr) * 64 + k] + b1[k];
            xs[rr][k] = vv > 0.f ? vv : 0.f;
        }
        __syncthreads();
        float acc[5] = {0.f, 0.f, 0.f, 0.f, 0.f};
#pragma unroll
        for (int k = 0; k < 64; ++k) {
            float xv = xs[r][k];
#pragma unroll
            for (int j = 0; j < 5; ++j) acc[j] += xv * Ws[k * 40 + cb + j];
        }
        int row = row0 + r;
        float di = dinv[row];
#pragma unroll
        for (int j = 0; j < 5; ++j) g2[(size_t)row * 40 + cb + j] = __float2half_rn(acc[j] * di);
    }
}

// ---- layer-2 aggregation + bias: out[v] = dinv[v]*(g2[v] + sum g2[s]) + b2 ----
// 40 halves = 80 B/edge: 10 lanes x 4 halves (8 B)
__global__ __launch_bounds__(256) void k_agg2(const __half* __restrict__ g2, const int* __restrict__ rowptr,
                                              const int* __restrict__ csr, const float* __restrict__ dinv,
                                              const float* __restrict__ b2, float* __restrict__ out, int n) {
    int lane = threadIdx.x & 63;
    int v = blockIdx.x * 4 + (threadIdx.x >> 6);
    if (v >= n) return;
    int beg = rowptr[v], end = rowptr[v + 1];
    int sub = lane >> 4, fl = lane & 15;
    float4 acc = {0.f, 0.f, 0.f, 0.f};
    if (fl < 10) {
        for (int i = beg + sub; i < end; i += 4) {
            int s = csr[i];
            acc_half4(acc, *reinterpret_cast<const uint2*>(&g2[(size_t)s * 40 + fl * 4]));
        }
    }
#pragma unroll
    for (int off = 16; off < 64; off <<= 1) {
        acc.x += __shfl_xor(acc.x, off);
        acc.y += __shfl_xor(acc.y, off);
        acc.z += __shfl_xor(acc.z, off);
        acc.w += __shfl_xor(acc.w, off);
    }
    if (sub == 0 && fl < 10) {
        float4 self = {0.f, 0.f, 0.f, 0.f};
        acc_half4(self, *reinterpret_cast<const uint2*>(&g2[(size_t)v * 40 + fl * 4]));
        float4 bb = *reinterpret_cast<const float4*>(&b2[fl * 4]);
        float d = dinv[v];
        float4 o;
        o.x = (acc.x + self.x) * d + bb.x;
        o.y = (acc.y + self.y) * d + bb.y;
        o.z = (acc.z + self.z) * d + bb.z;
        o.w = (acc.w + self.w) * d + bb.w;
        *reinterpret_cast<float4*>(&out[(size_t)v * 40 + fl * 4]) = o;
    }
}

extern "C" void kernel_launch(void* const* d_in, const int* in_sizes, int n_in,
                              void* d_out, int out_size, void* d_ws, size_t ws_size,
                              hipStream_t stream) {
    const float* x  = (const float*)d_in[0];
    const int*   ei = (const int*)d_in[1];
    const float* W1 = (const float*)d_in[2];
    const float* b1 = (const float*)d_in[3];
    const float* W2 = (const float*)d_in[4];
    const float* b2 = (const float*)d_in[5];
    float* out = (float*)d_out;

    int N = in_sizes[0] / 128;   // 100000
    int E = in_sizes[1] / 2;     // 1600000
    const int* src = ei;
    const int* dst = ei + E;

    int NB = (N + NPB - 1) / NPB;      // 391 buckets
    int chunk = (E + NCH - 1) / NCH;   // 6250
    int M = NB * NCH;                  // 100096 (assumes <= 128*SCAN_BLK)
    int nw = (M + SCAN_BLK - 1) / SCAN_BLK;  // 98

    char* w = (char*)d_ws;
    int*   ghist      = (int*)w;           w += (size_t)M * 4;
    int*   gbase      = (int*)w;           w += (size_t)M * 4;
    int*   bucketBase = (int*)w;           w += (size_t)(NB + 1) * 4 + 252;
    int*   wsum       = (int*)w;           w += 128 * 4;
    unsigned int* ebuf = (unsigned int*)w; w += (size_t)E * 4;
    int*   rowptr     = (int*)w;           w += (size_t)(N + 1) * 4 + 252;
    float* dinv       = (float*)w;         w += (size_t)N * 4 + 256;
    int*   csr        = (int*)w;           w += (size_t)E * 4;
    __half* g1        = (__half*)w;        w += (size_t)N * 64 * 2;
    float* agg1       = (float*)w;         w += (size_t)N * 64 * 4;
    __half* g2        = (__half*)w;        // N*40*2

    k_hist<<<NCH, 256, 0, stream>>>(dst, ghist, E, NB, chunk);
    k_scan_reduce<<<nw, 256, 0, stream>>>(ghist, wsum, M);
    k_scan_mid<<<1, 128, 0, stream>>>(wsum, bucketBase, nw, NB, E);
    k_scan_apply<<<nw, 256, 0, stream>>>(ghist, wsum, gbase, bucketBase, M);
    k_partition<<<NCH, 256, 0, stream>>>(src, dst, gbase, ebuf, E, NB, chunk);
    k_csr<<<NB, 256, 0, stream>>>(ebuf, bucketBase, rowptr, dinv, csr, N, E);

    int ntile = (N + 63) >> 6;   // 1563
    k_gemm1<<<ntile, 256, 0, stream>>>(x, W1, dinv, g1, N);
    k_agg1<<<(N + 3) / 4, 256, 0, stream>>>(g1, rowptr, csr, dinv, agg1, N);
    k_gemm2<<<1024, 256, 0, stream>>>(agg1, W2, b1, dinv, g2, N);
    k_agg2<<<(N + 3) / 4, 256, 0, stream>>>(g2, rowptr, csr, dinv, b2, out, N);
}

// Round 8
// 320.587 us; speedup vs baseline: 1.7298x; 1.0831x over previous
//
#include <hip/hip_runtime.h>
#include <hip/hip_fp16.h>

// GCN 2-layer via on-device CSR + gather-aggregation.
// out = A_norm * relu(A_norm * (X W1) + b1) * W2 + b2
// CSR build = two-level counting sort with locality-preserving writes.
// Gather buffers g1/g2 stored fp16; accumulation fp32.
// agg kernels: deep software-pipelined gathers (8 slots x uint4 for 64-feat,
// 2-deep prefetch) to maximize memory-level parallelism.

#define NPB 256              // nodes per bucket (pow2, dst>>8)
#define NB_MAX 512           // max buckets supported (N <= 131072)
#define NCH 256              // partition chunks (= WGs)
#define SCAN_BLK 1024        // elements per scan WG

// ---- Pass A: per-chunk bucket histogram -> ghist[b*NCH + w] ----
__global__ __launch_bounds__(256) void k_hist(const int* __restrict__ dst, int* __restrict__ ghist,
                                              int E, int NB, int chunk) {
    __shared__ int h[NB_MAX];
    int tid = threadIdx.x, w = blockIdx.x;
    for (int b = tid; b < NB; b += 256) h[b] = 0;
    __syncthreads();
    int beg = w * chunk, end = min(E, beg + chunk);
    for (int e = beg + tid; e < end; e += 256) atomicAdd(&h[dst[e] >> 8], 1);
    __syncthreads();
    for (int b = tid; b < NB; b += 256) ghist[b * NCH + w] = h[b];
}

// ---- 3-phase exclusive scan of ghist[M] -> gbase[M], bucketBase ----
__global__ __launch_bounds__(256) void k_scan_reduce(const int* __restrict__ ghist, int* __restrict__ wsum, int M) {
    __shared__ int s[256];
    int tid = threadIdx.x;
    int base = blockIdx.x * SCAN_BLK + tid * 4;
    int v = 0;
    if (base + 3 < M) {
        int4 r = *reinterpret_cast<const int4*>(&ghist[base]);
        v = r.x + r.y + r.z + r.w;
    } else {
        for (int j = 0; j < 4; ++j) if (base + j < M) v += ghist[base + j];
    }
    s[tid] = v;
    __syncthreads();
    for (int off = 128; off > 0; off >>= 1) {
        if (tid < off) s[tid] += s[tid + off];
        __syncthreads();
    }
    if (tid == 0) wsum[blockIdx.x] = s[0];
}

// single WG: exclusive-scan nw (<=128) block sums in place; set bucketBase[NB]=E
__global__ __launch_bounds__(128) void k_scan_mid(int* __restrict__ wsum, int* __restrict__ bucketBase,
                                                  int nw, int NB, int E) {
    __shared__ int s[128];
    int tid = threadIdx.x;
    int v = (tid < nw) ? wsum[tid] : 0;
    s[tid] = v;
    __syncthreads();
    for (int off = 1; off < 128; off <<= 1) {
        int add = (tid >= off) ? s[tid - off] : 0;
        __syncthreads();
        s[tid] += add;
        __syncthreads();
    }
    if (tid < nw) wsum[tid] = s[tid] - v;  // exclusive
    if (tid == 0) bucketBase[NB] = E;
}

__global__ __launch_bounds__(256) void k_scan_apply(const int* __restrict__ ghist, const int* __restrict__ wsum,
                                                    int* __restrict__ gbase, int* __restrict__ bucketBase, int M) {
    __shared__ int s[256];
    int tid = threadIdx.x;
    int base = blockIdx.x * SCAN_BLK + tid * 4;
    int e[4];
    int v = 0;
#pragma unroll
    for (int j = 0; j < 4; ++j) {
        int val = (base + j < M) ? ghist[base + j] : 0;
        e[j] = v;  // thread-local exclusive prefix
        v += val;
    }
    s[tid] = v;
    __syncthreads();
    for (int off = 1; off < 256; off <<= 1) {
        int add = (tid >= off) ? s[tid - off] : 0;
        __syncthreads();
        s[tid] += add;
        __syncthreads();
    }
    int tbase = wsum[blockIdx.x] + s[tid] - v;
#pragma unroll
    for (int j = 0; j < 4; ++j) {
        int i = base + j;
        if (i < M) {
            int g = tbase + e[j];
            gbase[i] = g;
            if ((i & (NCH - 1)) == 0) bucketBase[i / NCH] = g;  // first chunk of bucket
        }
    }
}

// ---- Pass B: partition edges into WG-private contiguous runs ----
__global__ __launch_bounds__(256) void k_partition(const int* __restrict__ src, const int* __restrict__ dst,
                                                   const int* __restrict__ gbase, unsigned int* __restrict__ ebuf,
                                                   int E, int NB, int chunk) {
    __shared__ int cur[NB_MAX];
    int tid = threadIdx.x, w = blockIdx.x;
    for (int b = tid; b < NB; b += 256) cur[b] = gbase[b * NCH + w];
    __syncthreads();
    int beg = w * chunk, end = min(E, beg + chunk);
    for (int e = beg + tid; e < end; e += 256) {
        int d = dst[e];
        int b = d >> 8;
        int pos = atomicAdd(&cur[b], 1);
        ebuf[pos] = (unsigned int)src[e] | ((unsigned int)(d & 255) << 24);  // src < 2^24
    }
}

// ---- Pass C: per-bucket counting sort -> rowptr, dinv, csr ----
__global__ __launch_bounds__(256) void k_csr(const unsigned int* __restrict__ ebuf,
                                             const int* __restrict__ bucketBase,
                                             int* __restrict__ rowptr, float* __restrict__ dinv,
                                             int* __restrict__ csr, int n, int E) {
    __shared__ int cnt[NPB];
    __shared__ int sc[NPB];
    __shared__ int cur[NPB];
    int tid = threadIdx.x, b = blockIdx.x;
    int ebeg = bucketBase[b], eend = bucketBase[b + 1];
    cnt[tid] = 0;
    __syncthreads();
    for (int i = ebeg + tid; i < eend; i += 256) atomicAdd(&cnt[ebuf[i] >> 24], 1);
    __syncthreads();
    int v = cnt[tid];
    sc[tid] = v;
    __syncthreads();
    for (int off = 1; off < 256; off <<= 1) {
        int add = (tid >= off) ? sc[tid - off] : 0;
        __syncthreads();
        sc[tid] += add;
        __syncthreads();
    }
    int ex = sc[tid] - v;  // exclusive
    cur[tid] = ex;
    int node = b * NPB + tid;
    if (node < n) {
        rowptr[node] = ebeg + ex;
        dinv[node] = rsqrtf((float)(v + 1));  // +1 self-loop
    }
    if (b == 0 && tid == 0) rowptr[n] = E;
    __syncthreads();
    for (int i = ebeg + tid; i < eend; i += 256) {
        unsigned int word = ebuf[i];
        int pos = atomicAdd(&cur[word >> 24], 1);
        csr[ebeg + pos] = (int)(word & 0xFFFFFFu);
    }
}

// ---- g1[row] = fp16( (x[row] @ W1) * dinv[row] );  [N,128]@[128,64] ----
// 64x64 tile/WG, 4x4 register tile/thread. Ws-only LDS (32 KB); x rows read
// directly from global (same-address lanes dedup'd by coalescer, L1/L2-hit).
__global__ __launch_bounds__(256) void k_gemm1(const float* __restrict__ x, const float* __restrict__ W1,
                                               const float* __restrict__ dinv, __half* __restrict__ g1,
                                               int n) {
    __shared__ float Ws[128 * 64];   // [k][col], same layout as W1 (32 KB)
    int tid = threadIdx.x;
    int tx = tid & 15, ty = tid >> 4;        // col-quad, row-quad
    for (int i = tid; i < 128 * 16; i += 256)
        reinterpret_cast<float4*>(Ws)[i] = reinterpret_cast<const float4*>(W1)[i];
    __syncthreads();

    int ntile = (n + 63) >> 6;
    for (int rg = blockIdx.x; rg < ntile; rg += gridDim.x) {
        int row0 = rg << 6;
        int r0 = row0 + ty * 4;
        const float* xp0 = x + (size_t)r0 * 128;
        bool full = (r0 + 3) < n;
        float acc[4][4] = {};
#pragma unroll 4
        for (int k = 0; k < 128; k += 4) {
            float xv[4][4], wv[4][4];
            if (full) {
#pragma unroll
                for (int i = 0; i < 4; ++i)
                    *reinterpret_cast<float4*>(xv[i]) = *reinterpret_cast<const float4*>(&xp0[(size_t)i * 128 + k]);
            } else {
#pragma unroll
                for (int i = 0; i < 4; ++i) {
                    float4 v = {0.f, 0.f, 0.f, 0.f};
                    if (r0 + i < n) v = *reinterpret_cast<const float4*>(&xp0[(size_t)i * 128 + k]);
                    *reinterpret_cast<float4*>(xv[i]) = v;
                }
            }
#pragma unroll
            for (int kk = 0; kk < 4; ++kk)
                *reinterpret_cast<float4*>(wv[kk]) = *reinterpret_cast<const float4*>(&Ws[(k + kk) * 64 + tx * 4]);
#pragma unroll
            for (int kk = 0; kk < 4; ++kk)
#pragma unroll
                for (int i = 0; i < 4; ++i)
#pragma unroll
                    for (int j = 0; j < 4; ++j)
                        acc[i][j] += xv[i][kk] * wv[kk][j];
        }
#pragma unroll
        for (int i = 0; i < 4; ++i) {
            int row = r0 + i;
            if (row < n) {
                float d = dinv[row];
                __half2 p0 = __halves2half2(__float2half_rn(acc[i][0] * d), __float2half_rn(acc[i][1] * d));
                __half2 p1 = __halves2half2(__float2half_rn(acc[i][2] * d), __float2half_rn(acc[i][3] * d));
                uint2 wq;
                wq.x = *reinterpret_cast<unsigned*>(&p0);
                wq.y = *reinterpret_cast<unsigned*>(&p1);
                *reinterpret_cast<uint2*>(&g1[(size_t)row * 64 + tx * 4]) = wq;
            }
        }
    }
}

__device__ __forceinline__ void acc_half4(float4& acc, uint2 r) {
    __half2 h0 = *reinterpret_cast<__half2*>(&r.x);
    __half2 h1 = *reinterpret_cast<__half2*>(&r.y);
    float2 f0 = __half22float2(h0);
    float2 f1 = __half22float2(h1);
    acc.x += f0.x; acc.y += f0.y; acc.z += f1.x; acc.w += f1.y;
}

__device__ __forceinline__ void acc_half8(float* acc, uint4 r) {
    const __half2* h = reinterpret_cast<const __half2*>(&r);
#pragma unroll
    for (int j = 0; j < 4; ++j) {
        float2 f = __half22float2(h[j]);
        acc[2 * j]     += f.x;
        acc[2 * j + 1] += f.y;
    }
}

// ---- layer-1 aggregation: agg1[v] = dinv[v]*(g1[v] + sum_{s in N(v)} g1[s]) ----
// one wave per node; 8 edge slots x 8 lanes x uint4 (16 B) = 128 B/edge,
// 2-deep software pipeline -> up to 16 row-reads in flight per wave.
__global__ __launch_bounds__(256) void k_agg1(const __half* __restrict__ g1, const int* __restrict__ rowptr,
                                              const int* __restrict__ csr, const float* __restrict__ dinv,
                                              float* __restrict__ agg1, int n) {
    int lane = threadIdx.x & 63;
    int v = blockIdx.x * 4 + (threadIdx.x >> 6);
    if (v >= n) return;
    int beg = rowptr[v], end = rowptr[v + 1];
    int sub = lane >> 3, fl = lane & 7;
    float acc[8] = {};
    int i = beg + sub;
    int s0 = (i < end) ? csr[i] : -1;
    int s1 = (i + 8 < end) ? csr[i + 8] : -1;
    while (s0 >= 0) {
        uint4 r0 = *reinterpret_cast<const uint4*>(&g1[(size_t)s0 * 64 + fl * 8]);
        uint4 r1;
        bool h1 = (s1 >= 0);
        if (h1) r1 = *reinterpret_cast<const uint4*>(&g1[(size_t)s1 * 64 + fl * 8]);
        i += 16;
        s0 = (i < end) ? csr[i] : -1;
        s1 = (i + 8 < end) ? csr[i + 8] : -1;
        acc_half8(acc, r0);
        if (h1) acc_half8(acc, r1);
    }
#pragma unroll
    for (int off = 8; off < 64; off <<= 1)
#pragma unroll
        for (int j = 0; j < 8; ++j) acc[j] += __shfl_xor(acc[j], off);
    if (sub == 0) {
        float self[8] = {};
        acc_half8(self, *reinterpret_cast<const uint4*>(&g1[(size_t)v * 64 + fl * 8]));
        float d = dinv[v];
        float4 o0, o1;
        o0.x = (acc[0] + self[0]) * d; o0.y = (acc[1] + self[1]) * d;
        o0.z = (acc[2] + self[2]) * d; o0.w = (acc[3] + self[3]) * d;
        o1.x = (acc[4] + self[4]) * d; o1.y = (acc[5] + self[5]) * d;
        o1.z = (acc[6] + self[6]) * d; o1.w = (acc[7] + self[7]) * d;
        *reinterpret_cast<float4*>(&agg1[(size_t)v * 64 + fl * 8]) = o0;
        *reinterpret_cast<float4*>(&agg1[(size_t)v * 64 + fl * 8 + 4]) = o1;
    }
}

// ---- g2[row] = fp16( (relu(agg1[row] + b1) @ W2) * dinv[row] );  [N,64]@[64,40] ----
__global__ __launch_bounds__(256) void k_gemm2(const float* __restrict__ agg1, const float* __restrict__ W2,
                                               const float* __restrict__ b1, const float* __restrict__ dinv,
                                               __half* __restrict__ g2, int n) {
    __shared__ float Ws[64 * 40];
    __shared__ float xs[32][65];
    int tid = threadIdx.x;
    for (int i = tid; i < 64 * 40; i += 256) Ws[i] = W2[i];
    int nrg = n >> 5;
    int r = tid >> 3, cb = (tid & 7) * 5;
    for (int rg = blockIdx.x; rg < nrg; rg += gridDim.x) {
        __syncthreads();
        int row0 = rg << 5;
        for (int i = tid; i < 32 * 64; i += 256) {
            int rr = i >> 6, k = i & 63;
            float vv = agg1[(row0 + rr) * 64 + k] + b1[k];
            xs[rr][k] = vv > 0.f ? vv : 0.f;
        }
        __syncthreads();
        float acc[5] = {0.f, 0.f, 0.f, 0.f, 0.f};
#pragma unroll
        for (int k = 0; k < 64; ++k) {
            float xv = xs[r][k];
#pragma unroll
            for (int j = 0; j < 5; ++j) acc[j] += xv * Ws[k * 40 + cb + j];
        }
        int row = row0 + r;
        float di = dinv[row];
#pragma unroll
        for (int j = 0; j < 5; ++j) g2[(size_t)row * 40 + cb + j] = __float2half_rn(acc[j] * di);
    }
}

// ---- layer-2 aggregation + bias: out[v] = dinv[v]*(g2[v] + sum g2[s]) + b2 ----
// 4 slots x 10 lanes x 8 B, 2-deep software pipeline.
__global__ __launch_bounds__(256) void k_agg2(const __half* __restrict__ g2, const int* __restrict__ rowptr,
                                              const int* __restrict__ csr, const float* __restrict__ dinv,
                                              const float* __restrict__ b2, float* __restrict__ out, int n) {
    int lane = threadIdx.x & 63;
    int v = blockIdx.x * 4 + (threadIdx.x >> 6);
    if (v >= n) return;
    int beg = rowptr[v], end = rowptr[v + 1];
    int sub = lane >> 4, fl = lane & 15;
    float4 acc = {0.f, 0.f, 0.f, 0.f};
    if (fl < 10) {
        int i = beg + sub;
        int s0 = (i < end) ? csr[i] : -1;
        int s1 = (i + 4 < end) ? csr[i + 4] : -1;
        while (s0 >= 0) {
            uint2 r0 = *reinterpret_cast<const uint2*>(&g2[(size_t)s0 * 40 + fl * 4]);
            uint2 r1;
            bool h1 = (s1 >= 0);
            if (h1) r1 = *reinterpret_cast<const uint2*>(&g2[(size_t)s1 * 40 + fl * 4]);
            i += 8;
            s0 = (i < end) ? csr[i] : -1;
            s1 = (i + 4 < end) ? csr[i + 4] : -1;
            acc_half4(acc, r0);
            if (h1) acc_half4(acc, r1);
        }
    }
#pragma unroll
    for (int off = 16; off < 64; off <<= 1) {
        acc.x += __shfl_xor(acc.x, off);
        acc.y += __shfl_xor(acc.y, off);
        acc.z += __shfl_xor(acc.z, off);
        acc.w += __shfl_xor(acc.w, off);
    }
    if (sub == 0 && fl < 10) {
        float4 self = {0.f, 0.f, 0.f, 0.f};
        acc_half4(self, *reinterpret_cast<const uint2*>(&g2[(size_t)v * 40 + fl * 4]));
        float4 bb = *reinterpret_cast<const float4*>(&b2[fl * 4]);
        float d = dinv[v];
        float4 o;
        o.x = (acc.x + self.x) * d + bb.x;
        o.y = (acc.y + self.y) * d + bb.y;
        o.z = (acc.z + self.z) * d + bb.z;
        o.w = (acc.w + self.w) * d + bb.w;
        *reinterpret_cast<float4*>(&out[(size_t)v * 40 + fl * 4]) = o;
    }
}

extern "C" void kernel_launch(void* const* d_in, const int* in_sizes, int n_in,
                              void* d_out, int out_size, void* d_ws, size_t ws_size,
                              hipStream_t stream) {
    const float* x  = (const float*)d_in[0];
    const int*   ei = (const int*)d_in[1];
    const float* W1 = (const float*)d_in[2];
    const float* b1 = (const float*)d_in[3];
    const float* W2 = (const float*)d_in[4];
    const float* b2 = (const float*)d_in[5];
    float* out = (float*)d_out;

    int N = in_sizes[0] / 128;   // 100000
    int E = in_sizes[1] / 2;     // 1600000
    const int* src = ei;
    const int* dst = ei + E;

    int NB = (N + NPB - 1) / NPB;      // 391 buckets
    int chunk = (E + NCH - 1) / NCH;   // 6250
    int M = NB * NCH;                  // 100096 (assumes <= 128*SCAN_BLK)
    int nw = (M + SCAN_BLK - 1) / SCAN_BLK;  // 98

    char* w = (char*)d_ws;
    int*   ghist      = (int*)w;           w += (size_t)M * 4;
    int*   gbase      = (int*)w;           w += (size_t)M * 4;
    int*   bucketBase = (int*)w;           w += (size_t)(NB + 1) * 4 + 252;
    int*   wsum       = (int*)w;           w += 128 * 4;
    unsigned int* ebuf = (unsigned int*)w; w += (size_t)E * 4;
    int*   rowptr     = (int*)w;           w += (size_t)(N + 1) * 4 + 252;
    float* dinv       = (float*)w;         w += (size_t)N * 4 + 256;
    int*   csr        = (int*)w;           w += (size_t)E * 4;
    __half* g1        = (__half*)w;        w += (size_t)N * 64 * 2;
    float* agg1       = (float*)w;         w += (size_t)N * 64 * 4;
    __half* g2        = (__half*)w;        // N*40*2

    k_hist<<<NCH, 256, 0, stream>>>(dst, ghist, E, NB, chunk);
    k_scan_reduce<<<nw, 256, 0, stream>>>(ghist, wsum, M);
    k_scan_mid<<<1, 128, 0, stream>>>(wsum, bucketBase, nw, NB, E);
    k_scan_apply<<<nw, 256, 0, stream>>>(ghist, wsum, gbase, bucketBase, M);
    k_partition<<<NCH, 256, 0, stream>>>(src, dst, gbase, ebuf, E, NB, chunk);
    k_csr<<<NB, 256, 0, stream>>>(ebuf, bucketBase, rowptr, dinv, csr, N, E);

    int ntile = (N + 63) >> 6;   // 1563
    k_gemm1<<<ntile, 256, 0, stream>>>(x, W1, dinv, g1, N);
    k_agg1<<<(N + 3) / 4, 256, 0, stream>>>(g1, rowptr, csr, dinv, agg1, N);
    k_gemm2<<<1024, 256, 0, stream>>>(agg1, W2, b1, dinv, g2, N);
    k_agg2<<<(N + 3) / 4, 256, 0, stream>>>(g2, rowptr, csr, dinv, b2, out, N);
}

// Round 9
// 284.629 us; speedup vs baseline: 1.9483x; 1.1263x over previous
//
#include <hip/hip_runtime.h>
#include <hip/hip_fp16.h>

// GCN 2-layer via on-device CSR + gather-aggregation.
// out = A_norm * relu(A_norm * (X W1) + b1) * W2 + b2
// CSR build = two-level counting sort with locality-preserving writes.
// Gather buffers g1/g2 stored fp16; accumulation fp32.
// gemm1 = MFMA (v_mfma_f32_16x16x32_f16): x,W1 cvt to fp16 in-flight,
//   A-frags in registers, W1^T fp16 in LDS, dinv fused at store.

#define NPB 256              // nodes per bucket (pow2, dst>>8)
#define NB_MAX 512           // max buckets supported (N <= 131072)
#define NCH 256              // partition chunks (= WGs)
#define SCAN_BLK 1024        // elements per scan WG

typedef _Float16 f16;
typedef f16 f16x8 __attribute__((ext_vector_type(8)));
typedef float f32x4 __attribute__((ext_vector_type(4)));

// ---- Pass A: per-chunk bucket histogram -> ghist[b*NCH + w] ----
__global__ __launch_bounds__(256) void k_hist(const int* __restrict__ dst, int* __restrict__ ghist,
                                              int E, int NB, int chunk) {
    __shared__ int h[NB_MAX];
    int tid = threadIdx.x, w = blockIdx.x;
    for (int b = tid; b < NB; b += 256) h[b] = 0;
    __syncthreads();
    int beg = w * chunk, end = min(E, beg + chunk);
    for (int e = beg + tid; e < end; e += 256) atomicAdd(&h[dst[e] >> 8], 1);
    __syncthreads();
    for (int b = tid; b < NB; b += 256) ghist[b * NCH + w] = h[b];
}

// ---- 3-phase exclusive scan of ghist[M] -> gbase[M], bucketBase ----
__global__ __launch_bounds__(256) void k_scan_reduce(const int* __restrict__ ghist, int* __restrict__ wsum, int M) {
    __shared__ int s[256];
    int tid = threadIdx.x;
    int base = blockIdx.x * SCAN_BLK + tid * 4;
    int v = 0;
    if (base + 3 < M) {
        int4 r = *reinterpret_cast<const int4*>(&ghist[base]);
        v = r.x + r.y + r.z + r.w;
    } else {
        for (int j = 0; j < 4; ++j) if (base + j < M) v += ghist[base + j];
    }
    s[tid] = v;
    __syncthreads();
    for (int off = 128; off > 0; off >>= 1) {
        if (tid < off) s[tid] += s[tid + off];
        __syncthreads();
    }
    if (tid == 0) wsum[blockIdx.x] = s[0];
}

// single WG: exclusive-scan nw (<=128) block sums in place; set bucketBase[NB]=E
__global__ __launch_bounds__(128) void k_scan_mid(int* __restrict__ wsum, int* __restrict__ bucketBase,
                                                  int nw, int NB, int E) {
    __shared__ int s[128];
    int tid = threadIdx.x;
    int v = (tid < nw) ? wsum[tid] : 0;
    s[tid] = v;
    __syncthreads();
    for (int off = 1; off < 128; off <<= 1) {
        int add = (tid >= off) ? s[tid - off] : 0;
        __syncthreads();
        s[tid] += add;
        __syncthreads();
    }
    if (tid < nw) wsum[tid] = s[tid] - v;  // exclusive
    if (tid == 0) bucketBase[NB] = E;
}

__global__ __launch_bounds__(256) void k_scan_apply(const int* __restrict__ ghist, const int* __restrict__ wsum,
                                                    int* __restrict__ gbase, int* __restrict__ bucketBase, int M) {
    __shared__ int s[256];
    int tid = threadIdx.x;
    int base = blockIdx.x * SCAN_BLK + tid * 4;
    int e[4];
    int v = 0;
#pragma unroll
    for (int j = 0; j < 4; ++j) {
        int val = (base + j < M) ? ghist[base + j] : 0;
        e[j] = v;  // thread-local exclusive prefix
        v += val;
    }
    s[tid] = v;
    __syncthreads();
    for (int off = 1; off < 256; off <<= 1) {
        int add = (tid >= off) ? s[tid - off] : 0;
        __syncthreads();
        s[tid] += add;
        __syncthreads();
    }
    int tbase = wsum[blockIdx.x] + s[tid] - v;
#pragma unroll
    for (int j = 0; j < 4; ++j) {
        int i = base + j;
        if (i < M) {
            int g = tbase + e[j];
            gbase[i] = g;
            if ((i & (NCH - 1)) == 0) bucketBase[i / NCH] = g;  // first chunk of bucket
        }
    }
}

// ---- Pass B: partition edges into WG-private contiguous runs ----
__global__ __launch_bounds__(256) void k_partition(const int* __restrict__ src, const int* __restrict__ dst,
                                                   const int* __restrict__ gbase, unsigned int* __restrict__ ebuf,
                                                   int E, int NB, int chunk) {
    __shared__ int cur[NB_MAX];
    int tid = threadIdx.x, w = blockIdx.x;
    for (int b = tid; b < NB; b += 256) cur[b] = gbase[b * NCH + w];
    __syncthreads();
    int beg = w * chunk, end = min(E, beg + chunk);
    for (int e = beg + tid; e < end; e += 256) {
        int d = dst[e];
        int b = d >> 8;
        int pos = atomicAdd(&cur[b], 1);
        ebuf[pos] = (unsigned int)src[e] | ((unsigned int)(d & 255) << 24);  // src < 2^24
    }
}

// ---- Pass C: per-bucket counting sort -> rowptr, dinv, csr ----
__global__ __launch_bounds__(256) void k_csr(const unsigned int* __restrict__ ebuf,
                                             const int* __restrict__ bucketBase,
                                             int* __restrict__ rowptr, float* __restrict__ dinv,
                                             int* __restrict__ csr, int n, int E) {
    __shared__ int cnt[NPB];
    __shared__ int sc[NPB];
    __shared__ int cur[NPB];
    int tid = threadIdx.x, b = blockIdx.x;
    int ebeg = bucketBase[b], eend = bucketBase[b + 1];
    cnt[tid] = 0;
    __syncthreads();
    for (int i = ebeg + tid; i < eend; i += 256) atomicAdd(&cnt[ebuf[i] >> 24], 1);
    __syncthreads();
    int v = cnt[tid];
    sc[tid] = v;
    __syncthreads();
    for (int off = 1; off < 256; off <<= 1) {
        int add = (tid >= off) ? sc[tid - off] : 0;
        __syncthreads();
        sc[tid] += add;
        __syncthreads();
    }
    int ex = sc[tid] - v;  // exclusive
    cur[tid] = ex;
    int node = b * NPB + tid;
    if (node < n) {
        rowptr[node] = ebeg + ex;
        dinv[node] = rsqrtf((float)(v + 1));  // +1 self-loop
    }
    if (b == 0 && tid == 0) rowptr[n] = E;
    __syncthreads();
    for (int i = ebeg + tid; i < eend; i += 256) {
        unsigned int word = ebuf[i];
        int pos = atomicAdd(&cur[word >> 24], 1);
        csr[ebeg + pos] = (int)(word & 0xFFFFFFu);
    }
}

// ---- g1[row] = fp16( (x[row] @ W1) * dinv[row] );  [N,128]@[128,64], MFMA ----
// WG = 4 waves, 64 rows/WG (16/wave). A-frags (x rows, cvt fp16) in registers;
// W1^T staged fp16 in LDS [col][k] (+8 pad). 16 MFMAs/wave (4 n-tiles x K=128).
// A layout: lane holds row (l&15), k=(l>>4)*8+j. B: col (l&15), same k.
// D layout (m89-verified): col=lane&15, row=(lane>>4)*4+reg.
__global__ __launch_bounds__(256) void k_gemm1(const float* __restrict__ x, const float* __restrict__ W1,
                                               const float* __restrict__ dinv, __half* __restrict__ g1,
                                               int n) {
    __shared__ f16 Wt[64][136];   // [col][k], pad 8 halves (17.4 KB)
    int tid = threadIdx.x;
    for (int i = tid; i < 128 * 64; i += 256) {
        int k = i >> 6, c = i & 63;
        Wt[c][k] = (f16)W1[i];
    }
    __syncthreads();

    int wv = tid >> 6, lane = tid & 63;
    int lrow = lane & 15, lk = (lane >> 4) * 8;
    int drow0 = (lane >> 4) * 4, dcol = lane & 15;

    int ntile = (n + 63) >> 6;
    for (int rg = blockIdx.x; rg < ntile; rg += gridDim.x) {
        int arow = rg * 64 + wv * 16 + lrow;
        f16x8 afrag[4];
        if (arow < n) {
            const float* xp = x + (size_t)arow * 128 + lk;
#pragma unroll
            for (int m = 0; m < 4; ++m) {
                float4 lo = *reinterpret_cast<const float4*>(xp + m * 32);
                float4 hi = *reinterpret_cast<const float4*>(xp + m * 32 + 4);
                f16x8 a;
                a[0] = (f16)lo.x; a[1] = (f16)lo.y; a[2] = (f16)lo.z; a[3] = (f16)lo.w;
                a[4] = (f16)hi.x; a[5] = (f16)hi.y; a[6] = (f16)hi.z; a[7] = (f16)hi.w;
                afrag[m] = a;
            }
        } else {
#pragma unroll
            for (int m = 0; m < 4; ++m) afrag[m] = (f16x8)(f16)0.f;
        }
        f32x4 accs[4];
#pragma unroll
        for (int t = 0; t < 4; ++t) {
            f32x4 acc = {0.f, 0.f, 0.f, 0.f};
#pragma unroll
            for (int m = 0; m < 4; ++m) {
                f16x8 b = *reinterpret_cast<const f16x8*>(&Wt[t * 16 + lrow][m * 32 + lk]);
                acc = __builtin_amdgcn_mfma_f32_16x16x32_f16(afrag[m], b, acc, 0, 0, 0);
            }
            accs[t] = acc;
        }
#pragma unroll
        for (int r = 0; r < 4; ++r) {
            int grow = rg * 64 + wv * 16 + drow0 + r;
            if (grow < n) {
                float dd = dinv[grow];
#pragma unroll
                for (int t = 0; t < 4; ++t)
                    g1[(size_t)grow * 64 + t * 16 + dcol] = __float2half_rn(accs[t][r] * dd);
            }
        }
    }
}

__device__ __forceinline__ void acc_half4(float4& acc, uint2 r) {
    __half2 h0 = *reinterpret_cast<__half2*>(&r.x);
    __half2 h1 = *reinterpret_cast<__half2*>(&r.y);
    float2 f0 = __half22float2(h0);
    float2 f1 = __half22float2(h1);
    acc.x += f0.x; acc.y += f0.y; acc.z += f1.x; acc.w += f1.y;
}

__device__ __forceinline__ void acc_half8(float* acc, uint4 r) {
    const __half2* h = reinterpret_cast<const __half2*>(&r);
#pragma unroll
    for (int j = 0; j < 4; ++j) {
        float2 f = __half22float2(h[j]);
        acc[2 * j]     += f.x;
        acc[2 * j + 1] += f.y;
    }
}

// ---- layer-1 aggregation: agg1[v] = dinv[v]*(g1[v] + sum_{s in N(v)} g1[s]) ----
// one wave per node; 8 edge slots x 8 lanes x uint4 (16 B) = 128 B/edge,
// 2-deep software pipeline -> up to 16 row-reads in flight per wave.
__global__ __launch_bounds__(256) void k_agg1(const __half* __restrict__ g1, const int* __restrict__ rowptr,
                                              const int* __restrict__ csr, const float* __restrict__ dinv,
                                              float* __restrict__ agg1, int n) {
    int lane = threadIdx.x & 63;
    int v = blockIdx.x * 4 + (threadIdx.x >> 6);
    if (v >= n) return;
    int beg = rowptr[v], end = rowptr[v + 1];
    int sub = lane >> 3, fl = lane & 7;
    float acc[8] = {};
    int i = beg + sub;
    int s0 = (i < end) ? csr[i] : -1;
    int s1 = (i + 8 < end) ? csr[i + 8] : -1;
    while (s0 >= 0) {
        uint4 r0 = *reinterpret_cast<const uint4*>(&g1[(size_t)s0 * 64 + fl * 8]);
        uint4 r1;
        bool h1 = (s1 >= 0);
        if (h1) r1 = *reinterpret_cast<const uint4*>(&g1[(size_t)s1 * 64 + fl * 8]);
        i += 16;
        s0 = (i < end) ? csr[i] : -1;
        s1 = (i + 8 < end) ? csr[i + 8] : -1;
        acc_half8(acc, r0);
        if (h1) acc_half8(acc, r1);
    }
#pragma unroll
    for (int off = 8; off < 64; off <<= 1)
#pragma unroll
        for (int j = 0; j < 8; ++j) acc[j] += __shfl_xor(acc[j], off);
    if (sub == 0) {
        float self[8] = {};
        acc_half8(self, *reinterpret_cast<const uint4*>(&g1[(size_t)v * 64 + fl * 8]));
        float d = dinv[v];
        float4 o0, o1;
        o0.x = (acc[0] + self[0]) * d; o0.y = (acc[1] + self[1]) * d;
        o0.z = (acc[2] + self[2]) * d; o0.w = (acc[3] + self[3]) * d;
        o1.x = (acc[4] + self[4]) * d; o1.y = (acc[5] + self[5]) * d;
        o1.z = (acc[6] + self[6]) * d; o1.w = (acc[7] + self[7]) * d;
        *reinterpret_cast<float4*>(&agg1[(size_t)v * 64 + fl * 8]) = o0;
        *reinterpret_cast<float4*>(&agg1[(size_t)v * 64 + fl * 8 + 4]) = o1;
    }
}

// ---- g2[row] = fp16( (relu(agg1[row] + b1) @ W2) * dinv[row] );  [N,64]@[64,40] ----
__global__ __launch_bounds__(256) void k_gemm2(const float* __restrict__ agg1, const float* __restrict__ W2,
                                               const float* __restrict__ b1, const float* __restrict__ dinv,
                                               __half* __restrict__ g2, int n) {
    __shared__ float Ws[64 * 40];
    __shared__ float xs[32][65];
    int tid = threadIdx.x;
    for (int i = tid; i < 64 * 40; i += 256) Ws[i] = W2[i];
    int nrg = n >> 5;
    int r = tid >> 3, cb = (tid & 7) * 5;
    for (int rg = blockIdx.x; rg < nrg; rg += gridDim.x) {
        __syncthreads();
        int row0 = rg << 5;
        for (int i = tid; i < 32 * 64; i += 256) {
            int rr = i >> 6, k = i & 63;
            float vv = agg1[(row0 + rr) * 64 + k] + b1[k];
            xs[rr][k] = vv > 0.f ? vv : 0.f;
        }
        __syncthreads();
        float acc[5] = {0.f, 0.f, 0.f, 0.f, 0.f};
#pragma unroll
        for (int k = 0; k < 64; ++k) {
            float xv = xs[r][k];
#pragma unroll
            for (int j = 0; j < 5; ++j) acc[j] += xv * Ws[k * 40 + cb + j];
        }
        int row = row0 + r;
        float di = dinv[row];
#pragma unroll
        for (int j = 0; j < 5; ++j) g2[(size_t)row * 40 + cb + j] = __float2half_rn(acc[j] * di);
    }
}

// ---- layer-2 aggregation + bias: out[v] = dinv[v]*(g2[v] + sum g2[s]) + b2 ----
// 4 slots x 10 lanes x 8 B, 2-deep software pipeline.
__global__ __launch_bounds__(256) void k_agg2(const __half* __restrict__ g2, const int* __restrict__ rowptr,
                                              const int* __restrict__ csr, const float* __restrict__ dinv,
                                              const float* __restrict__ b2, float* __restrict__ out, int n) {
    int lane = threadIdx.x & 63;
    int v = blockIdx.x * 4 + (threadIdx.x >> 6);
    if (v >= n) return;
    int beg = rowptr[v], end = rowptr[v + 1];
    int sub = lane >> 4, fl = lane & 15;
    float4 acc = {0.f, 0.f, 0.f, 0.f};
    if (fl < 10) {
        int i = beg + sub;
        int s0 = (i < end) ? csr[i] : -1;
        int s1 = (i + 4 < end) ? csr[i + 4] : -1;
        while (s0 >= 0) {
            uint2 r0 = *reinterpret_cast<const uint2*>(&g2[(size_t)s0 * 40 + fl * 4]);
            uint2 r1;
            bool h1 = (s1 >= 0);
            if (h1) r1 = *reinterpret_cast<const uint2*>(&g2[(size_t)s1 * 40 + fl * 4]);
            i += 8;
            s0 = (i < end) ? csr[i] : -1;
            s1 = (i + 4 < end) ? csr[i + 4] : -1;
            acc_half4(acc, r0);
            if (h1) acc_half4(acc, r1);
        }
    }
#pragma unroll
    for (int off = 16; off < 64; off <<= 1) {
        acc.x += __shfl_xor(acc.x, off);
        acc.y += __shfl_xor(acc.y, off);
        acc.z += __shfl_xor(acc.z, off);
        acc.w += __shfl_xor(acc.w, off);
    }
    if (sub == 0 && fl < 10) {
        float4 self = {0.f, 0.f, 0.f, 0.f};
        acc_half4(self, *reinterpret_cast<const uint2*>(&g2[(size_t)v * 40 + fl * 4]));
        float4 bb = *reinterpret_cast<const float4*>(&b2[fl * 4]);
        float d = dinv[v];
        float4 o;
        o.x = (acc.x + self.x) * d + bb.x;
        o.y = (acc.y + self.y) * d + bb.y;
        o.z = (acc.z + self.z) * d + bb.z;
        o.w = (acc.w + self.w) * d + bb.w;
        *reinterpret_cast<float4*>(&out[(size_t)v * 40 + fl * 4]) = o;
    }
}

extern "C" void kernel_launch(void* const* d_in, const int* in_sizes, int n_in,
                              void* d_out, int out_size, void* d_ws, size_t ws_size,
                              hipStream_t stream) {
    const float* x  = (const float*)d_in[0];
    const int*   ei = (const int*)d_in[1];
    const float* W1 = (const float*)d_in[2];
    const float* b1 = (const float*)d_in[3];
    const float* W2 = (const float*)d_in[4];
    const float* b2 = (const float*)d_in[5];
    float* out = (float*)d_out;

    int N = in_sizes[0] / 128;   // 100000
    int E = in_sizes[1] / 2;     // 1600000
    const int* src = ei;
    const int* dst = ei + E;

    int NB = (N + NPB - 1) / NPB;      // 391 buckets
    int chunk = (E + NCH - 1) / NCH;   // 6250
    int M = NB * NCH;                  // 100096 (assumes <= 128*SCAN_BLK)
    int nw = (M + SCAN_BLK - 1) / SCAN_BLK;  // 98

    char* w = (char*)d_ws;
    int*   ghist      = (int*)w;           w += (size_t)M * 4;
    int*   gbase      = (int*)w;           w += (size_t)M * 4;
    int*   bucketBase = (int*)w;           w += (size_t)(NB + 1) * 4 + 252;
    int*   wsum       = (int*)w;           w += 128 * 4;
    unsigned int* ebuf = (unsigned int*)w; w += (size_t)E * 4;
    int*   rowptr     = (int*)w;           w += (size_t)(N + 1) * 4 + 252;
    float* dinv       = (float*)w;         w += (size_t)N * 4 + 256;
    int*   csr        = (int*)w;           w += (size_t)E * 4;
    __half* g1        = (__half*)w;        w += (size_t)N * 64 * 2;
    float* agg1       = (float*)w;         w += (size_t)N * 64 * 4;
    __half* g2        = (__half*)w;        // N*40*2

    k_hist<<<NCH, 256, 0, stream>>>(dst, ghist, E, NB, chunk);
    k_scan_reduce<<<nw, 256, 0, stream>>>(ghist, wsum, M);
    k_scan_mid<<<1, 128, 0, stream>>>(wsum, bucketBase, nw, NB, E);
    k_scan_apply<<<nw, 256, 0, stream>>>(ghist, wsum, gbase, bucketBase, M);
    k_partition<<<NCH, 256, 0, stream>>>(src, dst, gbase, ebuf, E, NB, chunk);
    k_csr<<<NB, 256, 0, stream>>>(ebuf, bucketBase, rowptr, dinv, csr, N, E);

    k_gemm1<<<1024, 256, 0, stream>>>(x, W1, dinv, g1, N);
    k_agg1<<<(N + 3) / 4, 256, 0, stream>>>(g1, rowptr, csr, dinv, agg1, N);
    k_gemm2<<<1024, 256, 0, stream>>>(agg1, W2, b1, dinv, g2, N);
    k_agg2<<<(N + 3) / 4, 256, 0, stream>>>(g2, rowptr, csr, dinv, b2, out, N);
}